// Round 3
// baseline (1361.014 us; speedup 1.0000x reference)
//
#include <hip/hip_runtime.h>

// Problem constants (fixed by setup_inputs).
constexpr int N_NODES = 40960;
constexpr int E_EDGES = 131072;
constexpr int B_GRAPH = 1024;
constexpr int FXD  = 78;
constexpr int FXD2 = 156;
constexpr int FXD4 = 312;
constexpr int OD   = 128;
constexpr int FXT  = 37261;
constexpr int KP64 = 37312;            // FXT padded to mult of 64
constexpr int NPG  = N_NODES / B_GRAPH;
constexpr int NN2  = 2 * N_NODES;      // batched (both drug branches)
constexpr int EE2  = 2 * E_EDGES;

typedef unsigned short us16;
typedef __attribute__((ext_vector_type(8))) short short8;  // 8 bf16
typedef __attribute__((ext_vector_type(4))) float f32x4;

__device__ inline us16 f2bf(float f) {             // fp32 -> bf16 RNE
    unsigned u = __float_as_uint(f);
    return (us16)((u + 0x7FFF + ((u >> 16) & 1)) >> 16);
}
__device__ inline float ldf(const float* p) { return *p; }
__device__ inline float ldf(const us16* p) { return __uint_as_float(((unsigned)*p) << 16); }

// ---------------------------------------------------------------------------
// Cell-layer bf16 MFMA GEMM: cv1[1024x512] += An[1024xKP64] @ BwT^T.
// 128x128 tile, BK=64, split-K z=16, 2-deep register prefetch.
// Prefetch sets are NAMED arrays + 2-unrolled loop: every index is
// compile-time constant (rule #20 — runtime-indexed arrays go to scratch).
// ---------------------------------------------------------------------------
#define CG_STEP(pa, pb, it)                                                   \
    {                                                                         \
        __syncthreads();                                                      \
        _Pragma("unroll")                                                     \
        for (int q = 0; q < 4; ++q) {                                         \
            *(uint4*)&As[p][r][8 * q] = pa[q];                                \
            *(uint4*)&Bs[p][r][8 * q] = pb[q];                                \
        }                                                                     \
        __syncthreads();                                                      \
        if ((it) + 2 < nIt) {                                                 \
            const us16* Ap2 = Ap + (size_t)((it) + 2) * 64;                   \
            const us16* Bp2 = Bp + (size_t)((it) + 2) * 64;                   \
            _Pragma("unroll")                                                 \
            for (int q = 0; q < 4; ++q) {                                     \
                pa[q] = *(const uint4*)(Ap2 + 8 * q);                         \
                pb[q] = *(const uint4*)(Bp2 + 8 * q);                         \
            }                                                                 \
        }                                                                     \
        _Pragma("unroll")                                                     \
        for (int ks = 0; ks < 2; ++ks) {                                      \
            short8 af[4], bf[4];                                              \
            _Pragma("unroll")                                                 \
            for (int t = 0; t < 4; ++t) {                                     \
                af[t] = *(const short8*)&As[ks][wm + t * 16 + fr][fq];        \
                bf[t] = *(const short8*)&Bs[ks][wn + t * 16 + fr][fq];        \
            }                                                                 \
            _Pragma("unroll")                                                 \
            for (int mt = 0; mt < 4; ++mt)                                    \
                _Pragma("unroll")                                             \
                for (int nt = 0; nt < 4; ++nt)                                \
                    acc[mt][nt] = __builtin_amdgcn_mfma_f32_16x16x32_bf16(    \
                        af[mt], bf[nt], acc[mt][nt], 0, 0, 0);                \
        }                                                                     \
    }

__global__ __launch_bounds__(256, 2)
void mfma_cell_gemm(const us16* __restrict__ An, const us16* __restrict__ BwT,
                    float* __restrict__ C)
{
    __shared__ us16 As[2][128][40];     // [k-substep][row][32 + pad]
    __shared__ us16 Bs[2][128][40];
    const int tid = threadIdx.x;
    const int m0 = blockIdx.x * 128;          // gx = 8
    const int n0 = blockIdx.y * 128;          // gy = 4
    const int S  = KP64 / 64;                 // 583
    const int per = (S + gridDim.z - 1) / gridDim.z;
    const int s0 = blockIdx.z * per;
    const int s1 = min(S, s0 + per);
    const int nIt = s1 - s0;

    const int r = tid >> 1;                   // row 0..127
    const int p = tid & 1;                    // k-substep owned by this thread

    const us16* Ap = An  + (size_t)(m0 + r) * KP64 + s0 * 64 + p * 32;
    const us16* Bp = BwT + (size_t)(n0 + r) * KP64 + s0 * 64 + p * 32;

    const int wave = tid >> 6, lane = tid & 63;
    const int wm = (wave >> 1) * 64, wn = (wave & 1) * 64;
    const int fr = lane & 15, fq = (lane >> 4) * 8;

    f32x4 acc[4][4] = {};
    uint4 paA[4], pbA[4], paB[4], pbB[4];     // named 2-deep prefetch sets
    if (nIt > 0) {
#pragma unroll
        for (int q = 0; q < 4; ++q) {
            paA[q] = *(const uint4*)(Ap + 8 * q);
            pbA[q] = *(const uint4*)(Bp + 8 * q);
        }
    }
    if (nIt > 1) {
#pragma unroll
        for (int q = 0; q < 4; ++q) {
            paB[q] = *(const uint4*)(Ap + 64 + 8 * q);
            pbB[q] = *(const uint4*)(Bp + 64 + 8 * q);
        }
    }

    int it = 0;
    for (; it + 1 < nIt; it += 2) {
        CG_STEP(paA, pbA, it)
        CG_STEP(paB, pbB, it + 1)
    }
    if (it < nIt) CG_STEP(paA, pbA, it)

#pragma unroll
    for (int mt = 0; mt < 4; ++mt)
#pragma unroll
        for (int nt = 0; nt < 4; ++nt)
#pragma unroll
            for (int reg = 0; reg < 4; ++reg) {
                int row = m0 + wm + mt * 16 + (lane >> 4) * 4 + reg;
                int col = n0 + wn + nt * 16 + fr;
                atomicAdd(&C[(size_t)row * 512 + col], acc[mt][nt][reg]);
            }
}

// An[row][k] = bf16(cell[row][k] * invn[row]), zero-padded to KP64.
__global__ void convert_cell(const float* __restrict__ cell, const float* __restrict__ invn,
                             us16* __restrict__ An)
{
    const int row = blockIdx.y;
    const int k8 = (blockIdx.x * 256 + threadIdx.x) * 8;
    if (k8 >= KP64) return;
    const float s = invn[row];
    const float* src = cell + (size_t)row * FXT;
    us16 v[8];
#pragma unroll
    for (int j = 0; j < 8; ++j) {
        int k = k8 + j;
        v[j] = f2bf((k < FXT) ? src[k] * s : 0.0f);
    }
    *(uint4*)&An[(size_t)row * KP64 + k8] = *(uint4*)v;
}

// WT[n][k] = bf16(W[k][n]), k zero-padded to KPc. 32x32 tiled transpose.
__global__ __launch_bounds__(256)
void convert_wT(const float* __restrict__ W, us16* __restrict__ WT,
                int K, int Nn, int KPc)
{
    __shared__ float tile[32][33];
    const int k0 = blockIdx.x * 32;
    const int n0 = blockIdx.y * 32;
    const int c  = threadIdx.x & 31;
    const int r0 = threadIdx.x >> 5;
#pragma unroll
    for (int p = 0; p < 4; ++p) {
        int k = k0 + r0 + p * 8;
        tile[r0 + p * 8][c] = (k < K && n0 + c < Nn) ? W[(size_t)k * Nn + n0 + c] : 0.0f;
    }
    __syncthreads();
#pragma unroll
    for (int p = 0; p < 4; ++p) {
        int n = n0 + r0 + p * 8;
        if (n < Nn) WT[(size_t)n * KPc + k0 + c] = f2bf(tile[c][r0 + p * 8]);
    }
}

// Small padded weight transpose: WT[n][k] bf16, n in [0,NPr), k in [0,KPc),
// zero-filled outside the real K x Nn extent. Tiny matrices only.
__global__ void convert_wT_small(const float* __restrict__ W, us16* __restrict__ WT,
                                 int K, int Nn, int KPc, int NPr)
{
    int idx = blockIdx.x * 256 + threadIdx.x;
    if (idx >= NPr * KPc) return;
    int n = idx / KPc, k = idx - n * KPc;
    WT[idx] = (n < Nn && k < K) ? f2bf(W[(size_t)k * Nn + n]) : (us16)0;
}

// ---------------------------------------------------------------------------
// Drug-conv bf16 MFMA GEMM: C = relu(A @ WT^T + bias), bf16 out.
// A: [NN2][KA] bf16 (zero-padded K). WT: [NP][KA] bf16 (zero-padded rows).
// Block: 256 thr / 4 waves; BM=128 (wave=32 rows); NTILE=80 (5 n-frags).
// Whole B tile in LDS; A double-buffered per 32-k step.
// ---------------------------------------------------------------------------
template<int KA>
__global__ __launch_bounds__(256, 2)
void mfma_conv(const us16* __restrict__ A, const us16* __restrict__ BT,
               const float* __restrict__ bias, us16* __restrict__ C,
               int Nn, int ldc)
{
    constexpr int KS = KA / 32;
    __shared__ us16 As[2][128][40];
    __shared__ us16 Bs[80][KA + 8];
    const int tid = threadIdx.x;
    const int m0 = blockIdx.x * 128;
    const int n0 = blockIdx.y * 80;

    // B tile (80 x KA), read-once (hot in L2 across blocks)
    for (int idx = tid; idx < 80 * (KA / 8); idx += 256) {
        int nr = idx / (KA / 8), c8 = (idx - nr * (KA / 8)) * 8;
        *(uint4*)&Bs[nr][c8] = *(const uint4*)&BT[(size_t)(n0 + nr) * KA + c8];
    }

    const int r = tid >> 1, h = (tid & 1) * 16;
    const us16* Ap = A + (size_t)(m0 + r) * KA + h;
    *(uint4*)&As[0][r][h]     = *(const uint4*)Ap;
    *(uint4*)&As[0][r][h + 8] = *(const uint4*)(Ap + 8);
    __syncthreads();

    const int wave = tid >> 6, lane = tid & 63;
    const int wm = wave * 32;
    const int fr = lane & 15, fq = (lane >> 4) * 8;

    f32x4 acc[2][5] = {};
#pragma unroll
    for (int s = 0; s < KS; ++s) {
        const int cb = s & 1;
        if (s + 1 < KS) {                    // prefetch next chunk into other buffer
            uint4 t0 = *(const uint4*)(Ap + 32);
            uint4 t1 = *(const uint4*)(Ap + 40);
            Ap += 32;
            *(uint4*)&As[cb ^ 1][r][h]     = t0;
            *(uint4*)&As[cb ^ 1][r][h + 8] = t1;
        }
        short8 af[2], bf[5];
#pragma unroll
        for (int mt = 0; mt < 2; ++mt)
            af[mt] = *(const short8*)&As[cb][wm + mt * 16 + fr][fq];
#pragma unroll
        for (int nf = 0; nf < 5; ++nf)
            bf[nf] = *(const short8*)&Bs[nf * 16 + fr][s * 32 + fq];
#pragma unroll
        for (int mt = 0; mt < 2; ++mt)
#pragma unroll
            for (int nf = 0; nf < 5; ++nf)
                acc[mt][nf] = __builtin_amdgcn_mfma_f32_16x16x32_bf16(
                    af[mt], bf[nf], acc[mt][nf], 0, 0, 0);
        __syncthreads();
    }

#pragma unroll
    for (int mt = 0; mt < 2; ++mt)
#pragma unroll
        for (int nf = 0; nf < 5; ++nf) {
            const int col = n0 + nf * 16 + fr;
            if (col < Nn) {
                const float bv = bias[col];
#pragma unroll
                for (int reg = 0; reg < 4; ++reg) {
                    int row = m0 + wm + mt * 16 + (lane >> 4) * 4 + reg;
                    C[(size_t)row * ldc + col] = f2bf(fmaxf(acc[mt][nf][reg] + bv, 0.0f));
                }
            }
        }
}

// ---------------------------------------------------------------------------
// Batched (both graphs) edge sort + gather aggregation.
// ---------------------------------------------------------------------------
__global__ void deg_count_b(const int* __restrict__ ei1, const int* __restrict__ ei2,
                            int* cnt) {
    int i = blockIdx.x * blockDim.x + threadIdx.x;
    if (i >= EE2) return;
    int d = (i < E_EDGES) ? ei1[E_EDGES + i] : ei2[E_EDGES + (i - E_EDGES)] + N_NODES;
    atomicAdd(&cnt[d], 1);
}

__global__ __launch_bounds__(512)
void scan1(const int* __restrict__ cnt, int* base, int* aux, float* dinv) {
    __shared__ int s[512];
    const int tid = threadIdx.x;
    const int i = blockIdx.x * 512 + tid;
    int v = cnt[i];
    dinv[i] = rsqrtf((float)(v + 1));
    s[tid] = v;
    __syncthreads();
    for (int off = 1; off < 512; off <<= 1) {
        int t = (tid >= off) ? s[tid - off] : 0;
        __syncthreads();
        s[tid] += t;
        __syncthreads();
    }
    base[i] = s[tid] - v;
    if (tid == 511) aux[blockIdx.x] = s[511];
}

__global__ void scan2(int* aux, int nblk) {
    __shared__ int s[256];
    const int tid = threadIdx.x;
    int v = (tid < nblk) ? aux[tid] : 0;
    s[tid] = v;
    __syncthreads();
    for (int off = 1; off < 256; off <<= 1) {
        int t = (tid >= off) ? s[tid - off] : 0;
        __syncthreads();
        s[tid] += t;
        __syncthreads();
    }
    if (tid < nblk) aux[tid] = s[tid] - v;
}

__global__ __launch_bounds__(512)
void scan3(int* base, const int* __restrict__ aux) {
    int i = blockIdx.x * 512 + threadIdx.x;
    base[i] += aux[blockIdx.x];
    if (i == 0) base[NN2] = EE2;
}

__global__ void place_edges_b(const int* __restrict__ ei1, const int* __restrict__ ei2,
                              const float* __restrict__ dinv, const int* __restrict__ base,
                              int* cur, int* __restrict__ esrc, float* __restrict__ enorm) {
    int e = blockIdx.x * blockDim.x + threadIdx.x;
    if (e >= EE2) return;
    int s, d;
    if (e < E_EDGES) { s = ei1[e];            d = ei1[E_EDGES + e]; }
    else             { s = ei2[e - E_EDGES] + N_NODES;
                       d = ei2[E_EDGES + (e - E_EDGES)] + N_NODES; }
    int p = base[d] + atomicAdd(&cur[d], 1);
    esrc[p]  = s;
    enorm[p] = dinv[s] * dinv[d];
}

// out[row][0:kaout] = bf16( sum_edges h[src]*norm + h[row]*dinv^2 ), zero pad.
template<typename Tin, int CH>
__global__ __launch_bounds__(256)
void gather_bf(const Tin* __restrict__ hA, const Tin* __restrict__ hB, int st, int fi, int kaout,
               const float* __restrict__ dinv, const int* __restrict__ base,
               const int* __restrict__ esrc, const float* __restrict__ enorm,
               us16* __restrict__ out)
{
    const int row  = blockIdx.x * 4 + (threadIdx.x >> 6);
    const int lane = threadIdx.x & 63;
    const float d  = dinv[row];
    const float d2 = d * d;
    const Tin* hr = (row < N_NODES) ? hA + (size_t)row * st
                                    : hB + (size_t)(row - N_NODES) * st;
    float acc[CH];
#pragma unroll
    for (int c = 0; c < CH; ++c) {
        int f = lane + 64 * c;
        acc[c] = (f < fi) ? ldf(hr + f) * d2 : 0.0f;
    }
    const int b0 = base[row], b1 = base[row + 1];
    for (int j = b0; j < b1; ++j) {
        const int s = esrc[j];
        const float w = enorm[j];
        const Tin* hs = (s < N_NODES) ? hA + (size_t)s * st
                                      : hB + (size_t)(s - N_NODES) * st;
#pragma unroll
        for (int c = 0; c < CH; ++c) {
            int f = lane + 64 * c;
            if (f < fi) acc[c] = fmaf(ldf(hs + f), w, acc[c]);
        }
    }
    us16* orow = out + (size_t)row * kaout;
#pragma unroll
    for (int c = 0; c < CH; ++c) {
        int f = lane + 64 * c;
        if (f < kaout) orow[f] = f2bf(acc[c]);   // acc==0 for f>=fi -> zero pad
    }
}

// ---------------------------------------------------------------------------
__global__ void seg_max_bf(const us16* __restrict__ x, float* __restrict__ out,
                           int fo, int ld) {
    int f = blockIdx.x * blockDim.x + threadIdx.x;
    int g = blockIdx.y;
    if (f >= fo) return;
    const us16* xp = x + (size_t)g * NPG * ld + f;
    float v = -1e30f;
#pragma unroll 4
    for (int j = 0; j < NPG; ++j) v = fmaxf(v, ldf(xp + (size_t)j * ld));
    out[(size_t)g * fo + f] = v;
}

__global__ __launch_bounds__(256)
void row_invnorm(const float* __restrict__ cell, float* __restrict__ invn, int K) {
    int b = blockIdx.x;
    const float* row = cell + (size_t)b * K;
    float ss = 0.f;
    for (int k = threadIdx.x; k < K; k += 256) {
        float v = row[k];
        ss = fmaf(v, v, ss);
    }
    for (int off = 32; off > 0; off >>= 1) ss += __shfl_down(ss, off, 64);
    __shared__ float sred[4];
    int lane = threadIdx.x & 63, wv = threadIdx.x >> 6;
    if (lane == 0) sred[wv] = ss;
    __syncthreads();
    if (threadIdx.x == 0) {
        float nrm = sqrtf(sred[0] + sred[1] + sred[2] + sred[3]);
        invn[b] = 1.0f / fmaxf(nrm, 1e-12f);
    }
}

// C = act(A@B + bias). pre != null (K pow2): relu(A+pre) fused on load.
// half_off == 0: plain row addressing (rows can exceed 1024).
// half_off != 0: rows >= 1024 map to row-1024, column offset half_off.
template<bool RELU>
__global__ __launch_bounds__(256)
void gemv_rows4(const float* __restrict__ A, const float* __restrict__ B,
                const float* __restrict__ bias, const float* __restrict__ pre,
                float* __restrict__ C, int K, int N, int ldc, int half_off)
{
    __shared__ float As[4 * 512];
    const int tid = threadIdx.x;
    const int r0 = blockIdx.x * 4;
    if (pre) {
        for (int i = tid; i < 4 * K; i += 256)
            As[i] = fmaxf(A[(size_t)r0 * K + i] + pre[i & (K - 1)], 0.0f);
    } else {
        for (int i = tid; i < 4 * K; i += 256) As[i] = A[(size_t)r0 * K + i];
    }
    __syncthreads();
    float* Cb;
    if (half_off != 0)
        Cb = C + (size_t)(r0 & 1023) * ldc + ((r0 >= 1024) ? half_off : 0);
    else
        Cb = C + (size_t)r0 * ldc;
    for (int n = tid; n < N; n += 256) {
        float b0 = bias[n];
        float a0 = b0, a1 = b0, a2 = b0, a3 = b0;
        const float* Bp = B + n;
        for (int k = 0; k < K; ++k) {
            float b = Bp[(size_t)k * N];
            a0 = fmaf(As[k], b, a0);
            a1 = fmaf(As[K + k], b, a1);
            a2 = fmaf(As[2 * K + k], b, a2);
            a3 = fmaf(As[3 * K + k], b, a3);
        }
        if (RELU) { a0 = fmaxf(a0, 0.f); a1 = fmaxf(a1, 0.f); a2 = fmaxf(a2, 0.f); a3 = fmaxf(a3, 0.f); }
        Cb[0 * ldc + n] = a0;
        Cb[1 * ldc + n] = a1;
        Cb[2 * ldc + n] = a2;
        Cb[3 * ldc + n] = a3;
    }
}

__global__ void final_linear2(const float* __restrict__ x, const float* __restrict__ W,
                              const float* __restrict__ b, float* __restrict__ out) {
    int i = blockIdx.x * blockDim.x + threadIdx.x;
    if (i >= B_GRAPH * 2) return;
    int row = i >> 1, o = i & 1;
    const float* xr = x + (size_t)row * 128;
    float acc = b[o];
    for (int k = 0; k < 128; ++k) acc = fmaf(xr[k], W[k * 2 + o], acc);
    out[i] = acc;
}

// ---------------------------------------------------------------------------
extern "C" void kernel_launch(void* const* d_in, const int* in_sizes, int n_in,
                              void* d_out, int out_size, void* d_ws, size_t ws_size,
                              hipStream_t stream) {
    (void)in_sizes; (void)n_in; (void)out_size; (void)ws_size;
    const float* x1   = (const float*)d_in[0];
    const int*   ei1  = (const int*)d_in[1];
    const float* x2   = (const float*)d_in[3];
    const int*   ei2  = (const int*)d_in[4];
    const float* cell = (const float*)d_in[6];
    const float* Wc1 = (const float*)d_in[7];  const float* bc1 = (const float*)d_in[8];
    const float* Wc2 = (const float*)d_in[9];  const float* bc2 = (const float*)d_in[10];
    const float* Wc3 = (const float*)d_in[11]; const float* bc3 = (const float*)d_in[12];
    const float* Wg1 = (const float*)d_in[13]; const float* bg1 = (const float*)d_in[14];
    const float* Wg2 = (const float*)d_in[15]; const float* bg2 = (const float*)d_in[16];
    const float* Wr1 = (const float*)d_in[17]; const float* br1 = (const float*)d_in[18];
    const float* Wr2 = (const float*)d_in[19]; const float* br2 = (const float*)d_in[20];
    const float* Wr3 = (const float*)d_in[21]; const float* br3 = (const float*)d_in[22];
    const float* Wf1 = (const float*)d_in[23]; const float* bf1 = (const float*)d_in[24];
    const float* Wf2 = (const float*)d_in[25]; const float* bf2 = (const float*)d_in[26];
    const float* Wo  = (const float*)d_in[27]; const float* bo  = (const float*)d_in[28];
    float* out = (float*)d_out;

    // ---- workspace: persistent (~7 MB) + overlapped unions ----
    float* ws = (float*)d_ws;
    float* xc   = ws;  ws += (size_t)B_GRAPH * 384;
    float* invn = ws;  ws += B_GRAPH;
    float* cv1  = ws;  ws += (size_t)B_GRAPH * 512;
    float* cv2  = ws;  ws += (size_t)B_GRAPH * 256;
    float* f1   = ws;  ws += (size_t)B_GRAPH * 512;
    float* f2   = ws;  ws += (size_t)B_GRAPH * 128;
    float* dinv = ws;  ws += NN2;
    float* pool = ws;  ws += (size_t)2048 * FXD4;
    float* gb   = ws;  ws += (size_t)2048 * FXD2;

    // union A: cell-phase bf16 buffers (1536 x KP64 bf16 = 114.6 MB).
    // May overlap dinv/pool/gb: those are written only in the later drug phase,
    // and the cell phase is fully stream-ordered before it.
    us16* An  = (us16*)dinv;
    us16* BwT = An + (size_t)B_GRAPH * KP64;

    // union B: branch phase (used strictly after mfma_cell_gemm; ~81 MB).
    // Starts after gb so it does NOT overlap dinv/pool/gb (live in this phase).
    us16* Abuf = (us16*)ws;                        // gather out, NN2 x <=160 bf16
    us16* Hbuf = Abuf + (size_t)NN2 * 160;         // conv out,  NN2 x <=320 bf16
    us16* W1T  = Hbuf + (size_t)NN2 * 320;         // 80  x 96  (16B-aligned)
    us16* W2T  = W1T + 80 * 96;                    // 160 x 96
    us16* W3T  = W2T + 160 * 96;                   // 320 x 160
    float* enorm = (float*)(W3T + 320 * 160);
    int* cnt  = (int*)(enorm + EE2);
    int* cur  = cnt + NN2;
    int* base = cur + NN2;
    int* aux  = base + NN2 + 1;
    int* esrc = aux + 256;

    // ================= cell branch (bf16 MFMA) =================
    row_invnorm<<<B_GRAPH, 256, 0, stream>>>(cell, invn, FXT);
    convert_cell<<<dim3((KP64 / 8 + 255) / 256, B_GRAPH, 1), 256, 0, stream>>>(cell, invn, An);
    convert_wT<<<dim3(KP64 / 32, 512 / 32, 1), 256, 0, stream>>>(Wr1, BwT, FXT, 512, KP64);
    hipMemsetAsync(cv1, 0, (size_t)B_GRAPH * 512 * sizeof(float), stream);
    mfma_cell_gemm<<<dim3(8, 4, 16), 256, 0, stream>>>(An, BwT, cv1);
    // bias+relu on cv1 fused into the next gemv's A load (pre=br1, K=512 pow2)
    gemv_rows4<true><<<B_GRAPH / 4, 256, 0, stream>>>(cv1, Wr2, br2, br1, cv2, 512, 256, 256, 0);
    gemv_rows4<false><<<B_GRAPH / 4, 256, 0, stream>>>(cv2, Wr3, br3, nullptr, xc + 256, 256, OD, 384, 0);

    // ================= drug branches (batched, bf16 MFMA convs) =================
    hipMemsetAsync(cnt, 0, (size_t)2 * NN2 * sizeof(int), stream);   // cnt + cur
    deg_count_b<<<(EE2 + 255) / 256, 256, 0, stream>>>(ei1, ei2, cnt);
    scan1<<<NN2 / 512, 512, 0, stream>>>(cnt, base, aux, dinv);
    scan2<<<1, 256, 0, stream>>>(aux, NN2 / 512);
    scan3<<<NN2 / 512, 512, 0, stream>>>(base, aux);
    place_edges_b<<<(EE2 + 255) / 256, 256, 0, stream>>>(ei1, ei2, dinv, base, cur, esrc, enorm);

    // conv weights -> padded bf16 WT[n][k] (tiny; after cell phase frees union)
    convert_wT_small<<<(80 * 96 + 255) / 256, 256, 0, stream>>>(Wc1, W1T, FXD, FXD, 96, 80);
    convert_wT_small<<<(160 * 96 + 255) / 256, 256, 0, stream>>>(Wc2, W2T, FXD, FXD2, 96, 160);
    convert_wT_small<<<(320 * 160 + 255) / 256, 256, 0, stream>>>(Wc3, W3T, FXD2, FXD4, 160, 320);

    // conv1: gather(x) -> Abuf[96]; relu(Abuf@Wc1+bc1) -> Hbuf[80]
    gather_bf<float, 2><<<NN2 / 4, 256, 0, stream>>>(x1, x2, FXD, FXD, 96,
                                                     dinv, base, esrc, enorm, Abuf);
    mfma_conv<96><<<dim3(NN2 / 128, 1, 1), 256, 0, stream>>>(Abuf, W1T, bc1, Hbuf, FXD, 80);
    // conv2
    gather_bf<us16, 2><<<NN2 / 4, 256, 0, stream>>>(Hbuf, Hbuf + (size_t)N_NODES * 80, 80, FXD, 96,
                                                    dinv, base, esrc, enorm, Abuf);
    mfma_conv<96><<<dim3(NN2 / 128, 2, 1), 256, 0, stream>>>(Abuf, W2T, bc2, Hbuf, FXD2, 160);
    // conv3
    gather_bf<us16, 3><<<NN2 / 4, 256, 0, stream>>>(Hbuf, Hbuf + (size_t)N_NODES * 160, 160, FXD2, 160,
                                                    dinv, base, esrc, enorm, Abuf);
    mfma_conv<160><<<dim3(NN2 / 128, 4, 1), 256, 0, stream>>>(Abuf, W3T, bc3, Hbuf, FXD4, 320);

    // pool (2048 graphs) + fc
    seg_max_bf<<<dim3(2, 2048, 1), 256, 0, stream>>>(Hbuf, pool, FXD4, 320);
    gemv_rows4<true><<<2048 / 4, 256, 0, stream>>>(pool, Wg1, bg1, nullptr, gb, FXD4, FXD2, FXD2, 0);
    gemv_rows4<false><<<2048 / 4, 256, 0, stream>>>(gb, Wg2, bg2, nullptr, xc, FXD2, OD, 384, OD);

    // ================= final MLP =================
    gemv_rows4<true><<<B_GRAPH / 4, 256, 0, stream>>>(xc, Wf1, bf1, nullptr, f1, 384, 512, 512, 0);
    gemv_rows4<true><<<B_GRAPH / 4, 256, 0, stream>>>(f1, Wf2, bf2, nullptr, f2, 512, OD, OD, 0);
    final_linear2<<<(B_GRAPH * 2 + 255) / 256, 256, 0, stream>>>(f2, Wo, bo, out);
}

// Round 5
// 1177.990 us; speedup vs baseline: 1.1554x; 1.1554x over previous
//
#include <hip/hip_runtime.h>

// Problem constants (fixed by setup_inputs).
constexpr int N_NODES = 40960;
constexpr int E_EDGES = 131072;
constexpr int B_GRAPH = 1024;
constexpr int FXD  = 78;
constexpr int FXD2 = 156;
constexpr int FXD4 = 312;
constexpr int OD   = 128;
constexpr int FXT  = 37261;
constexpr int KP   = 37280;            // FXT padded to mult of 32
constexpr int NPG  = N_NODES / B_GRAPH;
constexpr int NN2  = 2 * N_NODES;      // batched (both drug branches)
constexpr int EE2  = 2 * E_EDGES;

typedef unsigned short us16;
typedef __attribute__((ext_vector_type(8))) short short8;  // 8 bf16
typedef __attribute__((ext_vector_type(4))) float f32x4;

__device__ inline us16 f2bf(float f) {             // fp32 -> bf16 RNE
    unsigned u = __float_as_uint(f);
    return (us16)((u + 0x7FFF + ((u >> 16) & 1)) >> 16);
}
__device__ inline float ldf(const float* p) { return *p; }
__device__ inline float ldf(const us16* p) { return __uint_as_float(((unsigned)*p) << 16); }

// ---------------------------------------------------------------------------
// Cell-layer bf16 MFMA GEMM: cv1[1024x512] += An[1024xKP] @ BwT^T.
// 128x128 tile, BK=32, split-K z=32, register-prefetch pipeline.
// PROVEN (R1): 121.5 us, VGPR 60, no scratch. Prefetch regs are individually
// named scalars — array formulations (even const-indexed) spilled to scratch.
// ---------------------------------------------------------------------------
__global__ __launch_bounds__(256, 2)
void mfma_cell_gemm(const us16* __restrict__ An, const us16* __restrict__ BwT,
                    float* __restrict__ C)
{
    __shared__ us16 As[128][40];
    __shared__ us16 Bs[128][40];
    const int tid = threadIdx.x;
    const int m0 = blockIdx.x * 128;          // gx = 8
    const int n0 = blockIdx.y * 128;          // gy = 4
    const int S  = KP / 32;                   // 1165
    const int per = (S + gridDim.z - 1) / gridDim.z;
    const int s0 = blockIdx.z * per;
    const int s1 = min(S, s0 + per);

    const int r = tid >> 1;
    const int h = (tid & 1) * 16;

    const us16* Ap = An  + (size_t)(m0 + r) * KP + s0 * 32 + h;
    const us16* Bp = BwT + (size_t)(n0 + r) * KP + s0 * 32 + h;

    const int wave = tid >> 6, lane = tid & 63;
    const int wm = (wave >> 1) * 64, wn = (wave & 1) * 64;
    const int fr = lane & 15, fq = (lane >> 4) * 8;

    f32x4 acc[4][4] = {};
    uint4 pa0, pa1, pb0, pb1;
    if (s0 < s1) {
        pa0 = *(const uint4*)Ap;       pa1 = *(const uint4*)(Ap + 8);
        pb0 = *(const uint4*)Bp;       pb1 = *(const uint4*)(Bp + 8);
    }
    for (int s = s0; s < s1; ++s) {
        __syncthreads();
        *(uint4*)&As[r][h] = pa0;  *(uint4*)&As[r][h + 8] = pa1;
        *(uint4*)&Bs[r][h] = pb0;  *(uint4*)&Bs[r][h + 8] = pb1;
        __syncthreads();
        if (s + 1 < s1) {           // prefetch next iter; latency hides behind MFMA
            Ap += 32; Bp += 32;
            pa0 = *(const uint4*)Ap;  pa1 = *(const uint4*)(Ap + 8);
            pb0 = *(const uint4*)Bp;  pb1 = *(const uint4*)(Bp + 8);
        }
        short8 af[4], bf[4];
#pragma unroll
        for (int t = 0; t < 4; ++t) {
            af[t] = *(const short8*)&As[wm + t * 16 + fr][fq];
            bf[t] = *(const short8*)&Bs[wn + t * 16 + fr][fq];
        }
#pragma unroll
        for (int mt = 0; mt < 4; ++mt)
#pragma unroll
            for (int nt = 0; nt < 4; ++nt)
                acc[mt][nt] = __builtin_amdgcn_mfma_f32_16x16x32_bf16(
                    af[mt], bf[nt], acc[mt][nt], 0, 0, 0);
    }
#pragma unroll
    for (int mt = 0; mt < 4; ++mt)
#pragma unroll
        for (int nt = 0; nt < 4; ++nt)
#pragma unroll
            for (int reg = 0; reg < 4; ++reg) {
                int row = m0 + wm + mt * 16 + (lane >> 4) * 4 + reg;
                int col = n0 + wn + nt * 16 + fr;
                atomicAdd(&C[(size_t)row * 512 + col], acc[mt][nt][reg]);
            }
}

// Fused: invn = 1/max(||row||,1e-12); An[row][k] = bf16(cell[row][k]*invn),
// zero-padded to KP. One block per row; second read hits L2 (146 KB row).
__global__ __launch_bounds__(256)
void norm_convert_cell(const float* __restrict__ cell, us16* __restrict__ An)
{
    const int row = blockIdx.x;
    const float* src = cell + (size_t)row * FXT;
    float ss = 0.f;
    for (int k = threadIdx.x; k < FXT; k += 256) {
        float v = src[k];
        ss = fmaf(v, v, ss);
    }
    for (int off = 32; off > 0; off >>= 1) ss += __shfl_down(ss, off, 64);
    __shared__ float sred[4];
    __shared__ float sinv;
    const int lane = threadIdx.x & 63, wv = threadIdx.x >> 6;
    if (lane == 0) sred[wv] = ss;
    __syncthreads();
    if (threadIdx.x == 0) {
        float nrm = sqrtf(sred[0] + sred[1] + sred[2] + sred[3]);
        sinv = 1.0f / fmaxf(nrm, 1e-12f);
    }
    __syncthreads();
    const float s = sinv;
    us16* dst = An + (size_t)row * KP;
    for (int k8 = threadIdx.x * 8; k8 < KP; k8 += 256 * 8) {
        us16 v[8];
#pragma unroll
        for (int j = 0; j < 8; ++j) {
            int k = k8 + j;
            v[j] = f2bf((k < FXT) ? src[k] * s : 0.0f);
        }
        *(uint4*)&dst[k8] = *(uint4*)v;
    }
}

// WT[n][k] = bf16(W[k][n]), k zero-padded to KPc. 32x32 tiled transpose.
__global__ __launch_bounds__(256)
void convert_wT(const float* __restrict__ W, us16* __restrict__ WT,
                int K, int Nn, int KPc)
{
    __shared__ float tile[32][33];
    const int k0 = blockIdx.x * 32;
    const int n0 = blockIdx.y * 32;
    const int c  = threadIdx.x & 31;
    const int r0 = threadIdx.x >> 5;
#pragma unroll
    for (int p = 0; p < 4; ++p) {
        int k = k0 + r0 + p * 8;
        tile[r0 + p * 8][c] = (k < K && n0 + c < Nn) ? W[(size_t)k * Nn + n0 + c] : 0.0f;
    }
    __syncthreads();
#pragma unroll
    for (int p = 0; p < 4; ++p) {
        int n = n0 + r0 + p * 8;
        if (n < Nn) WT[(size_t)n * KPc + k0 + c] = f2bf(tile[c][r0 + p * 8]);
    }
}

// Small padded weight transpose: WT[n][k] bf16, n in [0,NPr), k in [0,KPc),
// zero-filled outside the real K x Nn extent. Tiny matrices only.
__global__ void convert_wT_small(const float* __restrict__ W, us16* __restrict__ WT,
                                 int K, int Nn, int KPc, int NPr)
{
    int idx = blockIdx.x * 256 + threadIdx.x;
    if (idx >= NPr * KPc) return;
    int n = idx / KPc, k = idx - n * KPc;
    WT[idx] = (n < Nn && k < K) ? f2bf(W[(size_t)k * Nn + n]) : (us16)0;
}

// ---------------------------------------------------------------------------
// Drug-conv bf16 MFMA GEMM: C = relu(A @ WT^T + bias), bf16 out.
// A: [NN2][KA] bf16 (zero-padded K). WT: [NP][KA] bf16 (zero-padded rows).
// Block: 256 thr / 4 waves; BM=128 (wave=32 rows); NTILE=80 (5 n-frags).
// Whole B tile in LDS; A double-buffered per 32-k step.
// ---------------------------------------------------------------------------
template<int KA>
__global__ __launch_bounds__(256, 2)
void mfma_conv(const us16* __restrict__ A, const us16* __restrict__ BT,
               const float* __restrict__ bias, us16* __restrict__ C,
               int Nn, int ldc)
{
    constexpr int KS = KA / 32;
    __shared__ us16 As[2][128][40];
    __shared__ us16 Bs[80][KA + 8];
    const int tid = threadIdx.x;
    const int m0 = blockIdx.x * 128;
    const int n0 = blockIdx.y * 80;

    // B tile (80 x KA), read-once (hot in L2 across blocks)
    for (int idx = tid; idx < 80 * (KA / 8); idx += 256) {
        int nr = idx / (KA / 8), c8 = (idx - nr * (KA / 8)) * 8;
        *(uint4*)&Bs[nr][c8] = *(const uint4*)&BT[(size_t)(n0 + nr) * KA + c8];
    }

    const int r = tid >> 1, h = (tid & 1) * 16;
    const us16* Ap = A + (size_t)(m0 + r) * KA + h;
    *(uint4*)&As[0][r][h]     = *(const uint4*)Ap;
    *(uint4*)&As[0][r][h + 8] = *(const uint4*)(Ap + 8);
    __syncthreads();

    const int wave = tid >> 6, lane = tid & 63;
    const int wm = wave * 32;
    const int fr = lane & 15, fq = (lane >> 4) * 8;

    f32x4 acc[2][5] = {};
#pragma unroll
    for (int s = 0; s < KS; ++s) {
        const int cb = s & 1;
        if (s + 1 < KS) {                    // prefetch next chunk into other buffer
            uint4 t0 = *(const uint4*)(Ap + 32);
            uint4 t1 = *(const uint4*)(Ap + 40);
            Ap += 32;
            *(uint4*)&As[cb ^ 1][r][h]     = t0;
            *(uint4*)&As[cb ^ 1][r][h + 8] = t1;
        }
        short8 af[2], bf[5];
#pragma unroll
        for (int mt = 0; mt < 2; ++mt)
            af[mt] = *(const short8*)&As[cb][wm + mt * 16 + fr][fq];
#pragma unroll
        for (int nf = 0; nf < 5; ++nf)
            bf[nf] = *(const short8*)&Bs[nf * 16 + fr][s * 32 + fq];
#pragma unroll
        for (int mt = 0; mt < 2; ++mt)
#pragma unroll
            for (int nf = 0; nf < 5; ++nf)
                acc[mt][nf] = __builtin_amdgcn_mfma_f32_16x16x32_bf16(
                    af[mt], bf[nf], acc[mt][nf], 0, 0, 0);
        __syncthreads();
    }

#pragma unroll
    for (int mt = 0; mt < 2; ++mt)
#pragma unroll
        for (int nf = 0; nf < 5; ++nf) {
            const int col = n0 + nf * 16 + fr;
            if (col < Nn) {
                const float bv = bias[col];
#pragma unroll
                for (int reg = 0; reg < 4; ++reg) {
                    int row = m0 + wm + mt * 16 + (lane >> 4) * 4 + reg;
                    C[(size_t)row * ldc + col] = f2bf(fmaxf(acc[mt][nf][reg] + bv, 0.0f));
                }
            }
        }
}

// ---------------------------------------------------------------------------
// Batched (both graphs) edge sort + gather aggregation.
// ---------------------------------------------------------------------------
__global__ void deg_count_b(const int* __restrict__ ei1, const int* __restrict__ ei2,
                            int* cnt) {
    int i = blockIdx.x * blockDim.x + threadIdx.x;
    if (i >= EE2) return;
    int d = (i < E_EDGES) ? ei1[E_EDGES + i] : ei2[E_EDGES + (i - E_EDGES)] + N_NODES;
    atomicAdd(&cnt[d], 1);
}

__global__ __launch_bounds__(512)
void scan1(const int* __restrict__ cnt, int* base, int* aux, float* dinv) {
    __shared__ int s[512];
    const int tid = threadIdx.x;
    const int i = blockIdx.x * 512 + tid;
    int v = cnt[i];
    dinv[i] = rsqrtf((float)(v + 1));
    s[tid] = v;
    __syncthreads();
    for (int off = 1; off < 512; off <<= 1) {
        int t = (tid >= off) ? s[tid - off] : 0;
        __syncthreads();
        s[tid] += t;
        __syncthreads();
    }
    base[i] = s[tid] - v;
    if (tid == 511) aux[blockIdx.x] = s[511];
}

__global__ void scan2(int* aux, int nblk) {
    __shared__ int s[256];
    const int tid = threadIdx.x;
    int v = (tid < nblk) ? aux[tid] : 0;
    s[tid] = v;
    __syncthreads();
    for (int off = 1; off < 256; off <<= 1) {
        int t = (tid >= off) ? s[tid - off] : 0;
        __syncthreads();
        s[tid] += t;
        __syncthreads();
    }
    if (tid < nblk) aux[tid] = s[tid] - v;
}

__global__ __launch_bounds__(512)
void scan3(int* base, const int* __restrict__ aux) {
    int i = blockIdx.x * 512 + threadIdx.x;
    base[i] += aux[blockIdx.x];
    if (i == 0) base[NN2] = EE2;
}

__global__ void place_edges_b(const int* __restrict__ ei1, const int* __restrict__ ei2,
                              const float* __restrict__ dinv, const int* __restrict__ base,
                              int* cur, int* __restrict__ esrc, float* __restrict__ enorm) {
    int e = blockIdx.x * blockDim.x + threadIdx.x;
    if (e >= EE2) return;
    int s, d;
    if (e < E_EDGES) { s = ei1[e];            d = ei1[E_EDGES + e]; }
    else             { s = ei2[e - E_EDGES] + N_NODES;
                       d = ei2[E_EDGES + (e - E_EDGES)] + N_NODES; }
    int p = base[d] + atomicAdd(&cur[d], 1);
    esrc[p]  = s;
    enorm[p] = dinv[s] * dinv[d];
}

// out[row][0:kaout] = bf16( sum_edges h[src]*norm + h[row]*dinv^2 ), zero pad.
template<typename Tin, int CH>
__global__ __launch_bounds__(256)
void gather_bf(const Tin* __restrict__ hA, const Tin* __restrict__ hB, int st, int fi, int kaout,
               const float* __restrict__ dinv, const int* __restrict__ base,
               const int* __restrict__ esrc, const float* __restrict__ enorm,
               us16* __restrict__ out)
{
    const int row  = blockIdx.x * 4 + (threadIdx.x >> 6);
    const int lane = threadIdx.x & 63;
    const float d  = dinv[row];
    const float d2 = d * d;
    const Tin* hr = (row < N_NODES) ? hA + (size_t)row * st
                                    : hB + (size_t)(row - N_NODES) * st;
    float acc[CH];
#pragma unroll
    for (int c = 0; c < CH; ++c) {
        int f = lane + 64 * c;
        acc[c] = (f < fi) ? ldf(hr + f) * d2 : 0.0f;
    }
    const int b0 = base[row], b1 = base[row + 1];
    for (int j = b0; j < b1; ++j) {
        const int s = esrc[j];
        const float w = enorm[j];
        const Tin* hs = (s < N_NODES) ? hA + (size_t)s * st
                                      : hB + (size_t)(s - N_NODES) * st;
#pragma unroll
        for (int c = 0; c < CH; ++c) {
            int f = lane + 64 * c;
            if (f < fi) acc[c] = fmaf(ldf(hs + f), w, acc[c]);
        }
    }
    us16* orow = out + (size_t)row * kaout;
#pragma unroll
    for (int c = 0; c < CH; ++c) {
        int f = lane + 64 * c;
        if (f < kaout) orow[f] = f2bf(acc[c]);   // acc==0 for f>=fi -> zero pad
    }
}

// ---------------------------------------------------------------------------
__global__ void seg_max_bf(const us16* __restrict__ x, float* __restrict__ out,
                           int fo, int ld) {
    int f = blockIdx.x * blockDim.x + threadIdx.x;
    int g = blockIdx.y;
    if (f >= fo) return;
    const us16* xp = x + (size_t)g * NPG * ld + f;
    float v = -1e30f;
#pragma unroll 4
    for (int j = 0; j < NPG; ++j) v = fmaxf(v, ldf(xp + (size_t)j * ld));
    out[(size_t)g * fo + f] = v;
}

// C = act(A@B + bias). pre != null (K pow2): relu(A+pre) fused on load.
// half_off == 0: plain row addressing (rows can exceed 1024).
// half_off != 0: rows >= 1024 map to row-1024, column offset half_off.
template<bool RELU>
__global__ __launch_bounds__(256)
void gemv_rows4(const float* __restrict__ A, const float* __restrict__ B,
                const float* __restrict__ bias, const float* __restrict__ pre,
                float* __restrict__ C, int K, int N, int ldc, int half_off)
{
    __shared__ float As[4 * 512];
    const int tid = threadIdx.x;
    const int r0 = blockIdx.x * 4;
    if (pre) {
        for (int i = tid; i < 4 * K; i += 256)
            As[i] = fmaxf(A[(size_t)r0 * K + i] + pre[i & (K - 1)], 0.0f);
    } else {
        for (int i = tid; i < 4 * K; i += 256) As[i] = A[(size_t)r0 * K + i];
    }
    __syncthreads();
    float* Cb;
    if (half_off != 0)
        Cb = C + (size_t)(r0 & 1023) * ldc + ((r0 >= 1024) ? half_off : 0);
    else
        Cb = C + (size_t)r0 * ldc;
    for (int n = tid; n < N; n += 256) {
        float b0 = bias[n];
        float a0 = b0, a1 = b0, a2 = b0, a3 = b0;
        const float* Bp = B + n;
        for (int k = 0; k < K; ++k) {
            float b = Bp[(size_t)k * N];
            a0 = fmaf(As[k], b, a0);
            a1 = fmaf(As[K + k], b, a1);
            a2 = fmaf(As[2 * K + k], b, a2);
            a3 = fmaf(As[3 * K + k], b, a3);
        }
        if (RELU) { a0 = fmaxf(a0, 0.f); a1 = fmaxf(a1, 0.f); a2 = fmaxf(a2, 0.f); a3 = fmaxf(a3, 0.f); }
        Cb[0 * ldc + n] = a0;
        Cb[1 * ldc + n] = a1;
        Cb[2 * ldc + n] = a2;
        Cb[3 * ldc + n] = a3;
    }
}

__global__ void final_linear2(const float* __restrict__ x, const float* __restrict__ W,
                              const float* __restrict__ b, float* __restrict__ out) {
    int i = blockIdx.x * blockDim.x + threadIdx.x;
    if (i >= B_GRAPH * 2) return;
    int row = i >> 1, o = i & 1;
    const float* xr = x + (size_t)row * 128;
    float acc = b[o];
    for (int k = 0; k < 128; ++k) acc = fmaf(xr[k], W[k * 2 + o], acc);
    out[i] = acc;
}

// ---------------------------------------------------------------------------
extern "C" void kernel_launch(void* const* d_in, const int* in_sizes, int n_in,
                              void* d_out, int out_size, void* d_ws, size_t ws_size,
                              hipStream_t stream) {
    (void)in_sizes; (void)n_in; (void)out_size; (void)ws_size;
    const float* x1   = (const float*)d_in[0];
    const int*   ei1  = (const int*)d_in[1];
    const float* x2   = (const float*)d_in[3];
    const int*   ei2  = (const int*)d_in[4];
    const float* cell = (const float*)d_in[6];
    const float* Wc1 = (const float*)d_in[7];  const float* bc1 = (const float*)d_in[8];
    const float* Wc2 = (const float*)d_in[9];  const float* bc2 = (const float*)d_in[10];
    const float* Wc3 = (const float*)d_in[11]; const float* bc3 = (const float*)d_in[12];
    const float* Wg1 = (const float*)d_in[13]; const float* bg1 = (const float*)d_in[14];
    const float* Wg2 = (const float*)d_in[15]; const float* bg2 = (const float*)d_in[16];
    const float* Wr1 = (const float*)d_in[17]; const float* br1 = (const float*)d_in[18];
    const float* Wr2 = (const float*)d_in[19]; const float* br2 = (const float*)d_in[20];
    const float* Wr3 = (const float*)d_in[21]; const float* br3 = (const float*)d_in[22];
    const float* Wf1 = (const float*)d_in[23]; const float* bf1 = (const float*)d_in[24];
    const float* Wf2 = (const float*)d_in[25]; const float* bf2 = (const float*)d_in[26];
    const float* Wo  = (const float*)d_in[27]; const float* bo  = (const float*)d_in[28];
    float* out = (float*)d_out;

    // ---- workspace: persistent (~11.5 MB) + union region ----
    float* ws = (float*)d_ws;
    float* xc   = ws;  ws += (size_t)B_GRAPH * 384;
    float* invn = ws;  ws += B_GRAPH;      // (kept for layout stability; unused)
    float* cv1  = ws;  ws += (size_t)B_GRAPH * 512;
    float* cv2  = ws;  ws += (size_t)B_GRAPH * 256;
    float* f1   = ws;  ws += (size_t)B_GRAPH * 512;
    float* f2   = ws;  ws += (size_t)B_GRAPH * 128;
    float* dinv = ws;  ws += NN2;
    float* pool = ws;  ws += (size_t)2048 * FXD4;
    float* gb   = ws;  ws += (size_t)2048 * FXD2;
    (void)invn;

    // union A: cell phase bf16 buffers (1536 x KP bf16 = 114.5 MB)
    us16* An  = (us16*)ws;
    us16* BwT = An + (size_t)B_GRAPH * KP;

    // union B: branch phase (used strictly after mfma_cell_gemm; ~81 MB)
    us16* Abuf = (us16*)ws;                        // gather out, NN2 x <=160 bf16
    us16* Hbuf = Abuf + (size_t)NN2 * 160;         // conv out,  NN2 x <=320 bf16
    us16* W1T  = Hbuf + (size_t)NN2 * 320;         // 80  x 96  (16B-aligned)
    us16* W2T  = W1T + 80 * 96;                    // 160 x 96
    us16* W3T  = W2T + 160 * 96;                   // 320 x 160
    float* enorm = (float*)(W3T + 320 * 160);
    int* cnt  = (int*)(enorm + EE2);
    int* cur  = cnt + NN2;
    int* base = cur + NN2;
    int* aux  = base + NN2 + 1;
    int* esrc = aux + 256;

    // ================= cell branch (bf16 MFMA) =================
    norm_convert_cell<<<B_GRAPH, 256, 0, stream>>>(cell, An);
    convert_wT<<<dim3(KP / 32, 512 / 32, 1), 256, 0, stream>>>(Wr1, BwT, FXT, 512, KP);
    hipMemsetAsync(cv1, 0, (size_t)B_GRAPH * 512 * sizeof(float), stream);
    mfma_cell_gemm<<<dim3(8, 4, 32), 256, 0, stream>>>(An, BwT, cv1);
    // bias+relu on cv1 fused into the next gemv's A load (pre=br1, K=512 pow2)
    gemv_rows4<true><<<B_GRAPH / 4, 256, 0, stream>>>(cv1, Wr2, br2, br1, cv2, 512, 256, 256, 0);
    gemv_rows4<false><<<B_GRAPH / 4, 256, 0, stream>>>(cv2, Wr3, br3, nullptr, xc + 256, 256, OD, 384, 0);

    // ================= drug branches (batched, bf16 MFMA convs) =================
    hipMemsetAsync(cnt, 0, (size_t)2 * NN2 * sizeof(int), stream);   // cnt + cur
    deg_count_b<<<(EE2 + 255) / 256, 256, 0, stream>>>(ei1, ei2, cnt);
    scan1<<<NN2 / 512, 512, 0, stream>>>(cnt, base, aux, dinv);
    scan2<<<1, 256, 0, stream>>>(aux, NN2 / 512);
    scan3<<<NN2 / 512, 512, 0, stream>>>(base, aux);
    place_edges_b<<<(EE2 + 255) / 256, 256, 0, stream>>>(ei1, ei2, dinv, base, cur, esrc, enorm);

    // conv weights -> padded bf16 WT[n][k] (tiny; after cell phase frees union)
    convert_wT_small<<<(80 * 96 + 255) / 256, 256, 0, stream>>>(Wc1, W1T, FXD, FXD, 96, 80);
    convert_wT_small<<<(160 * 96 + 255) / 256, 256, 0, stream>>>(Wc2, W2T, FXD, FXD2, 96, 160);
    convert_wT_small<<<(320 * 160 + 255) / 256, 256, 0, stream>>>(Wc3, W3T, FXD2, FXD4, 160, 320);

    // conv1: gather(x) -> Abuf[96]; relu(Abuf@Wc1+bc1) -> Hbuf[80]
    gather_bf<float, 2><<<NN2 / 4, 256, 0, stream>>>(x1, x2, FXD, FXD, 96,
                                                     dinv, base, esrc, enorm, Abuf);
    mfma_conv<96><<<dim3(NN2 / 128, 1, 1), 256, 0, stream>>>(Abuf, W1T, bc1, Hbuf, FXD, 80);
    // conv2
    gather_bf<us16, 2><<<NN2 / 4, 256, 0, stream>>>(Hbuf, Hbuf + (size_t)N_NODES * 80, 80, FXD, 96,
                                                    dinv, base, esrc, enorm, Abuf);
    mfma_conv<96><<<dim3(NN2 / 128, 2, 1), 256, 0, stream>>>(Abuf, W2T, bc2, Hbuf, FXD2, 160);
    // conv3
    gather_bf<us16, 3><<<NN2 / 4, 256, 0, stream>>>(Hbuf, Hbuf + (size_t)N_NODES * 160, 160, FXD2, 160,
                                                    dinv, base, esrc, enorm, Abuf);
    mfma_conv<160><<<dim3(NN2 / 128, 4, 1), 256, 0, stream>>>(Abuf, W3T, bc3, Hbuf, FXD4, 320);

    // pool (2048 graphs) + fc
    seg_max_bf<<<dim3(2, 2048, 1), 256, 0, stream>>>(Hbuf, pool, FXD4, 320);
    gemv_rows4<true><<<2048 / 4, 256, 0, stream>>>(pool, Wg1, bg1, nullptr, gb, FXD4, FXD2, FXD2, 0);
    gemv_rows4<false><<<2048 / 4, 256, 0, stream>>>(gb, Wg2, bg2, nullptr, xc, FXD2, OD, 384, OD);

    // ================= final MLP =================
    gemv_rows4<true><<<B_GRAPH / 4, 256, 0, stream>>>(xc, Wf1, bf1, nullptr, f1, 384, 512, 512, 0);
    gemv_rows4<true><<<B_GRAPH / 4, 256, 0, stream>>>(f1, Wf2, bf2, nullptr, f2, 512, OD, OD, 0);
    final_linear2<<<(B_GRAPH * 2 + 255) / 256, 256, 0, stream>>>(f2, Wo, bo, out);
}

// Round 6
// 1137.589 us; speedup vs baseline: 1.1964x; 1.0355x over previous
//
#include <hip/hip_runtime.h>

// Problem constants (fixed by setup_inputs).
constexpr int N_NODES = 40960;
constexpr int E_EDGES = 131072;
constexpr int B_GRAPH = 1024;
constexpr int FXD  = 78;
constexpr int FXD2 = 156;
constexpr int FXD4 = 312;
constexpr int OD   = 128;
constexpr int FXT  = 37261;
constexpr int KP   = 37280;            // FXT padded to mult of 32
constexpr int NPG  = N_NODES / B_GRAPH;
constexpr int NN2  = 2 * N_NODES;      // batched (both drug branches)
constexpr int EE2  = 2 * E_EDGES;

typedef unsigned short us16;
typedef __attribute__((ext_vector_type(8))) short short8;  // 8 bf16
typedef __attribute__((ext_vector_type(4))) float f32x4;

__device__ inline us16 f2bf(float f) {             // fp32 -> bf16 RNE
    unsigned u = __float_as_uint(f);
    return (us16)((u + 0x7FFF + ((u >> 16) & 1)) >> 16);
}
__device__ inline float ldf(const float* p) { return *p; }
__device__ inline float ldf(const us16* p) { return __uint_as_float(((unsigned)*p) << 16); }

// ---------------------------------------------------------------------------
// Cell-layer bf16 MFMA GEMM: cv1[1024x512] += An[1024xKP] @ BwT^T.
// 128x128 tile, BK=32, split-K z=32, register-prefetch pipeline.
// PROVEN (R1): 121.5 us, VGPR 60, no scratch. Prefetch regs are individually
// named scalars — array formulations (even const-indexed) spilled to scratch.
// ---------------------------------------------------------------------------
__global__ __launch_bounds__(256, 2)
void mfma_cell_gemm(const us16* __restrict__ An, const us16* __restrict__ BwT,
                    float* __restrict__ C)
{
    __shared__ us16 As[128][40];
    __shared__ us16 Bs[128][40];
    const int tid = threadIdx.x;
    const int m0 = blockIdx.x * 128;          // gx = 8
    const int n0 = blockIdx.y * 128;          // gy = 4
    const int S  = KP / 32;                   // 1165
    const int per = (S + gridDim.z - 1) / gridDim.z;
    const int s0 = blockIdx.z * per;
    const int s1 = min(S, s0 + per);

    const int r = tid >> 1;
    const int h = (tid & 1) * 16;

    const us16* Ap = An  + (size_t)(m0 + r) * KP + s0 * 32 + h;
    const us16* Bp = BwT + (size_t)(n0 + r) * KP + s0 * 32 + h;

    const int wave = tid >> 6, lane = tid & 63;
    const int wm = (wave >> 1) * 64, wn = (wave & 1) * 64;
    const int fr = lane & 15, fq = (lane >> 4) * 8;

    f32x4 acc[4][4] = {};
    uint4 pa0, pa1, pb0, pb1;
    if (s0 < s1) {
        pa0 = *(const uint4*)Ap;       pa1 = *(const uint4*)(Ap + 8);
        pb0 = *(const uint4*)Bp;       pb1 = *(const uint4*)(Bp + 8);
    }
    for (int s = s0; s < s1; ++s) {
        __syncthreads();
        *(uint4*)&As[r][h] = pa0;  *(uint4*)&As[r][h + 8] = pa1;
        *(uint4*)&Bs[r][h] = pb0;  *(uint4*)&Bs[r][h + 8] = pb1;
        __syncthreads();
        if (s + 1 < s1) {           // prefetch next iter; latency hides behind MFMA
            Ap += 32; Bp += 32;
            pa0 = *(const uint4*)Ap;  pa1 = *(const uint4*)(Ap + 8);
            pb0 = *(const uint4*)Bp;  pb1 = *(const uint4*)(Bp + 8);
        }
        short8 af[4], bf[4];
#pragma unroll
        for (int t = 0; t < 4; ++t) {
            af[t] = *(const short8*)&As[wm + t * 16 + fr][fq];
            bf[t] = *(const short8*)&Bs[wn + t * 16 + fr][fq];
        }
#pragma unroll
        for (int mt = 0; mt < 4; ++mt)
#pragma unroll
            for (int nt = 0; nt < 4; ++nt)
                acc[mt][nt] = __builtin_amdgcn_mfma_f32_16x16x32_bf16(
                    af[mt], bf[nt], acc[mt][nt], 0, 0, 0);
    }
#pragma unroll
    for (int mt = 0; mt < 4; ++mt)
#pragma unroll
        for (int nt = 0; nt < 4; ++nt)
#pragma unroll
            for (int reg = 0; reg < 4; ++reg) {
                int row = m0 + wm + mt * 16 + (lane >> 4) * 4 + reg;
                int col = n0 + wn + nt * 16 + fr;
                atomicAdd(&C[(size_t)row * 512 + col], acc[mt][nt][reg]);
            }
}

// Fused: invn = 1/max(||row||,1e-12); An[row][k] = bf16(cell[row][k]*invn),
// zero-padded to KP. One 512-thr block per row; pass-1 uses aligned float4
// loads (rows misaligned by row%4 elems since FXT%4==1 -> scalar pre/tail);
// pass-2 re-read hits L3 (146 MB < 256 MB).
__global__ __launch_bounds__(512)
void norm_convert_cell(const float* __restrict__ cell, us16* __restrict__ An)
{
    const int row = blockIdx.x;
    const int tid = threadIdx.x;
    const float* src = cell + (size_t)row * FXT;

    // ---- pass 1: sum of squares (float4 main body) ----
    const int pre = (4 - (row & 3)) & 3;          // elems until 16B alignment
    float ss = 0.f;
    if (tid < pre) { float v = src[tid]; ss = fmaf(v, v, ss); }
    const int nv4 = (FXT - pre) >> 2;
    const float4* src4 = (const float4*)(src + pre);
    for (int k = tid; k < nv4; k += 512) {
        float4 v = src4[k];
        ss = fmaf(v.x, v.x, ss);
        ss = fmaf(v.y, v.y, ss);
        ss = fmaf(v.z, v.z, ss);
        ss = fmaf(v.w, v.w, ss);
    }
    for (int k = pre + nv4 * 4 + tid; k < FXT; k += 512) {
        float v = src[k];
        ss = fmaf(v, v, ss);
    }
    for (int off = 32; off > 0; off >>= 1) ss += __shfl_down(ss, off, 64);
    __shared__ float sred[8];
    __shared__ float sinv;
    const int lane = tid & 63, wv = tid >> 6;
    if (lane == 0) sred[wv] = ss;
    __syncthreads();
    if (tid == 0) {
        float t = 0.f;
#pragma unroll
        for (int i = 0; i < 8; ++i) t += sred[i];
        sinv = 1.0f / fmaxf(sqrtf(t), 1e-12f);
    }
    __syncthreads();

    // ---- pass 2: scaled bf16 convert (8 indep loads/lane + 16B store) ----
    const float s = sinv;
    us16* dst = An + (size_t)row * KP;
    for (int k8 = tid * 8; k8 < KP; k8 += 512 * 8) {
        us16 v[8];
#pragma unroll
        for (int j = 0; j < 8; ++j) {
            int k = k8 + j;
            v[j] = f2bf((k < FXT) ? src[k] * s : 0.0f);
        }
        *(uint4*)&dst[k8] = *(uint4*)v;
    }
}

// WT[n][k] = bf16(W[k][n]), k zero-padded to KPc. 32x32 tiled transpose.
__global__ __launch_bounds__(256)
void convert_wT(const float* __restrict__ W, us16* __restrict__ WT,
                int K, int Nn, int KPc)
{
    __shared__ float tile[32][33];
    const int k0 = blockIdx.x * 32;
    const int n0 = blockIdx.y * 32;
    const int c  = threadIdx.x & 31;
    const int r0 = threadIdx.x >> 5;
#pragma unroll
    for (int p = 0; p < 4; ++p) {
        int k = k0 + r0 + p * 8;
        tile[r0 + p * 8][c] = (k < K && n0 + c < Nn) ? W[(size_t)k * Nn + n0 + c] : 0.0f;
    }
    __syncthreads();
#pragma unroll
    for (int p = 0; p < 4; ++p) {
        int n = n0 + r0 + p * 8;
        if (n < Nn) WT[(size_t)n * KPc + k0 + c] = f2bf(tile[c][r0 + p * 8]);
    }
}

// Small padded weight transpose: WT[n][k] bf16, n in [0,NPr), k in [0,KPc),
// zero-filled outside the real K x Nn extent. Tiny matrices only.
__global__ void convert_wT_small(const float* __restrict__ W, us16* __restrict__ WT,
                                 int K, int Nn, int KPc, int NPr)
{
    int idx = blockIdx.x * 256 + threadIdx.x;
    if (idx >= NPr * KPc) return;
    int n = idx / KPc, k = idx - n * KPc;
    WT[idx] = (n < Nn && k < K) ? f2bf(W[(size_t)k * Nn + n]) : (us16)0;
}

// ---------------------------------------------------------------------------
// Drug-conv bf16 MFMA GEMM: C = relu(A @ WT^T + bias), bf16 out.
// A: [NN2][KA] bf16 (zero-padded K). WT: [NP][KA] bf16 (zero-padded rows).
// Block: 256 thr / 4 waves; BM=128 (wave=32 rows); NTILE=80 (5 n-frags).
// Whole B tile in LDS; A double-buffered per 32-k step.
// ---------------------------------------------------------------------------
template<int KA>
__global__ __launch_bounds__(256, 2)
void mfma_conv(const us16* __restrict__ A, const us16* __restrict__ BT,
               const float* __restrict__ bias, us16* __restrict__ C,
               int Nn, int ldc)
{
    constexpr int KS = KA / 32;
    __shared__ us16 As[2][128][40];
    __shared__ us16 Bs[80][KA + 8];
    const int tid = threadIdx.x;
    const int m0 = blockIdx.x * 128;
    const int n0 = blockIdx.y * 80;

    // B tile (80 x KA), read-once (hot in L2 across blocks)
    for (int idx = tid; idx < 80 * (KA / 8); idx += 256) {
        int nr = idx / (KA / 8), c8 = (idx - nr * (KA / 8)) * 8;
        *(uint4*)&Bs[nr][c8] = *(const uint4*)&BT[(size_t)(n0 + nr) * KA + c8];
    }

    const int r = tid >> 1, h = (tid & 1) * 16;
    const us16* Ap = A + (size_t)(m0 + r) * KA + h;
    *(uint4*)&As[0][r][h]     = *(const uint4*)Ap;
    *(uint4*)&As[0][r][h + 8] = *(const uint4*)(Ap + 8);
    __syncthreads();

    const int wave = tid >> 6, lane = tid & 63;
    const int wm = wave * 32;
    const int fr = lane & 15, fq = (lane >> 4) * 8;

    f32x4 acc[2][5] = {};
#pragma unroll
    for (int s = 0; s < KS; ++s) {
        const int cb = s & 1;
        if (s + 1 < KS) {                    // prefetch next chunk into other buffer
            uint4 t0 = *(const uint4*)(Ap + 32);
            uint4 t1 = *(const uint4*)(Ap + 40);
            Ap += 32;
            *(uint4*)&As[cb ^ 1][r][h]     = t0;
            *(uint4*)&As[cb ^ 1][r][h + 8] = t1;
        }
        short8 af[2], bf[5];
#pragma unroll
        for (int mt = 0; mt < 2; ++mt)
            af[mt] = *(const short8*)&As[cb][wm + mt * 16 + fr][fq];
#pragma unroll
        for (int nf = 0; nf < 5; ++nf)
            bf[nf] = *(const short8*)&Bs[nf * 16 + fr][s * 32 + fq];
#pragma unroll
        for (int mt = 0; mt < 2; ++mt)
#pragma unroll
            for (int nf = 0; nf < 5; ++nf)
                acc[mt][nf] = __builtin_amdgcn_mfma_f32_16x16x32_bf16(
                    af[mt], bf[nf], acc[mt][nf], 0, 0, 0);
        __syncthreads();
    }

#pragma unroll
    for (int mt = 0; mt < 2; ++mt)
#pragma unroll
        for (int nf = 0; nf < 5; ++nf) {
            const int col = n0 + nf * 16 + fr;
            if (col < Nn) {
                const float bv = bias[col];
#pragma unroll
                for (int reg = 0; reg < 4; ++reg) {
                    int row = m0 + wm + mt * 16 + (lane >> 4) * 4 + reg;
                    C[(size_t)row * ldc + col] = f2bf(fmaxf(acc[mt][nf][reg] + bv, 0.0f));
                }
            }
        }
}

// ---------------------------------------------------------------------------
// Batched (both graphs) edge sort + gather aggregation.
// ---------------------------------------------------------------------------
__global__ void deg_count_b(const int* __restrict__ ei1, const int* __restrict__ ei2,
                            int* cnt) {
    int i = blockIdx.x * blockDim.x + threadIdx.x;
    if (i >= EE2) return;
    int d = (i < E_EDGES) ? ei1[E_EDGES + i] : ei2[E_EDGES + (i - E_EDGES)] + N_NODES;
    atomicAdd(&cnt[d], 1);
}

__global__ __launch_bounds__(512)
void scan1(const int* __restrict__ cnt, int* base, int* aux, float* dinv) {
    __shared__ int s[512];
    const int tid = threadIdx.x;
    const int i = blockIdx.x * 512 + tid;
    int v = cnt[i];
    dinv[i] = rsqrtf((float)(v + 1));
    s[tid] = v;
    __syncthreads();
    for (int off = 1; off < 512; off <<= 1) {
        int t = (tid >= off) ? s[tid - off] : 0;
        __syncthreads();
        s[tid] += t;
        __syncthreads();
    }
    base[i] = s[tid] - v;
    if (tid == 511) aux[blockIdx.x] = s[511];
}

__global__ void scan2(int* aux, int nblk) {
    __shared__ int s[256];
    const int tid = threadIdx.x;
    int v = (tid < nblk) ? aux[tid] : 0;
    s[tid] = v;
    __syncthreads();
    for (int off = 1; off < 256; off <<= 1) {
        int t = (tid >= off) ? s[tid - off] : 0;
        __syncthreads();
        s[tid] += t;
        __syncthreads();
    }
    if (tid < nblk) aux[tid] = s[tid] - v;
}

__global__ __launch_bounds__(512)
void scan3(int* base, const int* __restrict__ aux) {
    int i = blockIdx.x * 512 + threadIdx.x;
    base[i] += aux[blockIdx.x];
    if (i == 0) base[NN2] = EE2;
}

__global__ void place_edges_b(const int* __restrict__ ei1, const int* __restrict__ ei2,
                              const float* __restrict__ dinv, const int* __restrict__ base,
                              int* cur, int* __restrict__ esrc, float* __restrict__ enorm) {
    int e = blockIdx.x * blockDim.x + threadIdx.x;
    if (e >= EE2) return;
    int s, d;
    if (e < E_EDGES) { s = ei1[e];            d = ei1[E_EDGES + e]; }
    else             { s = ei2[e - E_EDGES] + N_NODES;
                       d = ei2[E_EDGES + (e - E_EDGES)] + N_NODES; }
    int p = base[d] + atomicAdd(&cur[d], 1);
    esrc[p]  = s;
    enorm[p] = dinv[s] * dinv[d];
}

// out[row][0:kaout] = bf16( sum_edges h[src]*norm + h[row]*dinv^2 ), zero pad.
template<typename Tin, int CH>
__global__ __launch_bounds__(256)
void gather_bf(const Tin* __restrict__ hA, const Tin* __restrict__ hB, int st, int fi, int kaout,
               const float* __restrict__ dinv, const int* __restrict__ base,
               const int* __restrict__ esrc, const float* __restrict__ enorm,
               us16* __restrict__ out)
{
    const int row  = blockIdx.x * 4 + (threadIdx.x >> 6);
    const int lane = threadIdx.x & 63;
    const float d  = dinv[row];
    const float d2 = d * d;
    const Tin* hr = (row < N_NODES) ? hA + (size_t)row * st
                                    : hB + (size_t)(row - N_NODES) * st;
    float acc[CH];
#pragma unroll
    for (int c = 0; c < CH; ++c) {
        int f = lane + 64 * c;
        acc[c] = (f < fi) ? ldf(hr + f) * d2 : 0.0f;
    }
    const int b0 = base[row], b1 = base[row + 1];
    for (int j = b0; j < b1; ++j) {
        const int s = esrc[j];
        const float w = enorm[j];
        const Tin* hs = (s < N_NODES) ? hA + (size_t)s * st
                                      : hB + (size_t)(s - N_NODES) * st;
#pragma unroll
        for (int c = 0; c < CH; ++c) {
            int f = lane + 64 * c;
            if (f < fi) acc[c] = fmaf(ldf(hs + f), w, acc[c]);
        }
    }
    us16* orow = out + (size_t)row * kaout;
#pragma unroll
    for (int c = 0; c < CH; ++c) {
        int f = lane + 64 * c;
        if (f < kaout) orow[f] = f2bf(acc[c]);   // acc==0 for f>=fi -> zero pad
    }
}

// ---------------------------------------------------------------------------
__global__ void seg_max_bf(const us16* __restrict__ x, float* __restrict__ out,
                           int fo, int ld) {
    int f = blockIdx.x * blockDim.x + threadIdx.x;
    int g = blockIdx.y;
    if (f >= fo) return;
    const us16* xp = x + (size_t)g * NPG * ld + f;
    float v = -1e30f;
#pragma unroll 4
    for (int j = 0; j < NPG; ++j) v = fmaxf(v, ldf(xp + (size_t)j * ld));
    out[(size_t)g * fo + f] = v;
}

// C = act(A@B + bias). pre != null (K pow2): relu(A+pre) fused on load.
// half_off == 0: plain row addressing (rows can exceed 1024).
// half_off != 0: rows >= 1024 map to row-1024, column offset half_off.
template<bool RELU>
__global__ __launch_bounds__(256)
void gemv_rows4(const float* __restrict__ A, const float* __restrict__ B,
                const float* __restrict__ bias, const float* __restrict__ pre,
                float* __restrict__ C, int K, int N, int ldc, int half_off)
{
    __shared__ float As[4 * 512];
    const int tid = threadIdx.x;
    const int r0 = blockIdx.x * 4;
    if (pre) {
        for (int i = tid; i < 4 * K; i += 256)
            As[i] = fmaxf(A[(size_t)r0 * K + i] + pre[i & (K - 1)], 0.0f);
    } else {
        for (int i = tid; i < 4 * K; i += 256) As[i] = A[(size_t)r0 * K + i];
    }
    __syncthreads();
    float* Cb;
    if (half_off != 0)
        Cb = C + (size_t)(r0 & 1023) * ldc + ((r0 >= 1024) ? half_off : 0);
    else
        Cb = C + (size_t)r0 * ldc;
    for (int n = tid; n < N; n += 256) {
        float b0 = bias[n];
        float a0 = b0, a1 = b0, a2 = b0, a3 = b0;
        const float* Bp = B + n;
        for (int k = 0; k < K; ++k) {
            float b = Bp[(size_t)k * N];
            a0 = fmaf(As[k], b, a0);
            a1 = fmaf(As[K + k], b, a1);
            a2 = fmaf(As[2 * K + k], b, a2);
            a3 = fmaf(As[3 * K + k], b, a3);
        }
        if (RELU) { a0 = fmaxf(a0, 0.f); a1 = fmaxf(a1, 0.f); a2 = fmaxf(a2, 0.f); a3 = fmaxf(a3, 0.f); }
        Cb[0 * ldc + n] = a0;
        Cb[1 * ldc + n] = a1;
        Cb[2 * ldc + n] = a2;
        Cb[3 * ldc + n] = a3;
    }
}

__global__ void final_linear2(const float* __restrict__ x, const float* __restrict__ W,
                              const float* __restrict__ b, float* __restrict__ out) {
    int i = blockIdx.x * blockDim.x + threadIdx.x;
    if (i >= B_GRAPH * 2) return;
    int row = i >> 1, o = i & 1;
    const float* xr = x + (size_t)row * 128;
    float acc = b[o];
    for (int k = 0; k < 128; ++k) acc = fmaf(xr[k], W[k * 2 + o], acc);
    out[i] = acc;
}

// ---------------------------------------------------------------------------
extern "C" void kernel_launch(void* const* d_in, const int* in_sizes, int n_in,
                              void* d_out, int out_size, void* d_ws, size_t ws_size,
                              hipStream_t stream) {
    (void)in_sizes; (void)n_in; (void)out_size; (void)ws_size;
    const float* x1   = (const float*)d_in[0];
    const int*   ei1  = (const int*)d_in[1];
    const float* x2   = (const float*)d_in[3];
    const int*   ei2  = (const int*)d_in[4];
    const float* cell = (const float*)d_in[6];
    const float* Wc1 = (const float*)d_in[7];  const float* bc1 = (const float*)d_in[8];
    const float* Wc2 = (const float*)d_in[9];  const float* bc2 = (const float*)d_in[10];
    const float* Wc3 = (const float*)d_in[11]; const float* bc3 = (const float*)d_in[12];
    const float* Wg1 = (const float*)d_in[13]; const float* bg1 = (const float*)d_in[14];
    const float* Wg2 = (const float*)d_in[15]; const float* bg2 = (const float*)d_in[16];
    const float* Wr1 = (const float*)d_in[17]; const float* br1 = (const float*)d_in[18];
    const float* Wr2 = (const float*)d_in[19]; const float* br2 = (const float*)d_in[20];
    const float* Wr3 = (const float*)d_in[21]; const float* br3 = (const float*)d_in[22];
    const float* Wf1 = (const float*)d_in[23]; const float* bf1 = (const float*)d_in[24];
    const float* Wf2 = (const float*)d_in[25]; const float* bf2 = (const float*)d_in[26];
    const float* Wo  = (const float*)d_in[27]; const float* bo  = (const float*)d_in[28];
    float* out = (float*)d_out;

    // ---- workspace: persistent (~11.5 MB) + union region ----
    float* ws = (float*)d_ws;
    float* xc   = ws;  ws += (size_t)B_GRAPH * 384;
    float* invn = ws;  ws += B_GRAPH;      // (kept for layout stability; unused)
    float* cv1  = ws;  ws += (size_t)B_GRAPH * 512;
    float* cv2  = ws;  ws += (size_t)B_GRAPH * 256;
    float* f1   = ws;  ws += (size_t)B_GRAPH * 512;
    float* f2   = ws;  ws += (size_t)B_GRAPH * 128;
    float* dinv = ws;  ws += NN2;
    float* pool = ws;  ws += (size_t)2048 * FXD4;
    float* gb   = ws;  ws += (size_t)2048 * FXD2;
    (void)invn;

    // union A: cell phase bf16 buffers (1536 x KP bf16 = 114.5 MB)
    us16* An  = (us16*)ws;
    us16* BwT = An + (size_t)B_GRAPH * KP;

    // union B: branch phase (used strictly after mfma_cell_gemm; ~81 MB)
    us16* Abuf = (us16*)ws;                        // gather out, NN2 x <=160 bf16
    us16* Hbuf = Abuf + (size_t)NN2 * 160;         // conv out,  NN2 x <=320 bf16
    us16* W1T  = Hbuf + (size_t)NN2 * 320;         // 80  x 96  (16B-aligned)
    us16* W2T  = W1T + 80 * 96;                    // 160 x 96
    us16* W3T  = W2T + 160 * 96;                   // 320 x 160
    float* enorm = (float*)(W3T + 320 * 160);
    int* cnt  = (int*)(enorm + EE2);
    int* cur  = cnt + NN2;
    int* base = cur + NN2;
    int* aux  = base + NN2 + 1;
    int* esrc = aux + 256;

    // ================= cell branch (bf16 MFMA) =================
    norm_convert_cell<<<B_GRAPH, 512, 0, stream>>>(cell, An);
    convert_wT<<<dim3(KP / 32, 512 / 32, 1), 256, 0, stream>>>(Wr1, BwT, FXT, 512, KP);
    hipMemsetAsync(cv1, 0, (size_t)B_GRAPH * 512 * sizeof(float), stream);
    mfma_cell_gemm<<<dim3(8, 4, 32), 256, 0, stream>>>(An, BwT, cv1);
    // bias+relu on cv1 fused into the next gemv's A load (pre=br1, K=512 pow2)
    gemv_rows4<true><<<B_GRAPH / 4, 256, 0, stream>>>(cv1, Wr2, br2, br1, cv2, 512, 256, 256, 0);
    gemv_rows4<false><<<B_GRAPH / 4, 256, 0, stream>>>(cv2, Wr3, br3, nullptr, xc + 256, 256, OD, 384, 0);

    // ================= drug branches (batched, bf16 MFMA convs) =================
    hipMemsetAsync(cnt, 0, (size_t)2 * NN2 * sizeof(int), stream);   // cnt + cur
    deg_count_b<<<(EE2 + 255) / 256, 256, 0, stream>>>(ei1, ei2, cnt);
    scan1<<<NN2 / 512, 512, 0, stream>>>(cnt, base, aux, dinv);
    scan2<<<1, 256, 0, stream>>>(aux, NN2 / 512);
    scan3<<<NN2 / 512, 512, 0, stream>>>(base, aux);
    place_edges_b<<<(EE2 + 255) / 256, 256, 0, stream>>>(ei1, ei2, dinv, base, cur, esrc, enorm);

    // conv weights -> padded bf16 WT[n][k] (tiny; after cell phase frees union)
    convert_wT_small<<<(80 * 96 + 255) / 256, 256, 0, stream>>>(Wc1, W1T, FXD, FXD, 96, 80);
    convert_wT_small<<<(160 * 96 + 255) / 256, 256, 0, stream>>>(Wc2, W2T, FXD, FXD2, 96, 160);
    convert_wT_small<<<(320 * 160 + 255) / 256, 256, 0, stream>>>(Wc3, W3T, FXD2, FXD4, 160, 320);

    // conv1: gather(x) -> Abuf[96]; relu(Abuf@Wc1+bc1) -> Hbuf[80]
    gather_bf<float, 2><<<NN2 / 4, 256, 0, stream>>>(x1, x2, FXD, FXD, 96,
                                                     dinv, base, esrc, enorm, Abuf);
    mfma_conv<96><<<dim3(NN2 / 128, 1, 1), 256, 0, stream>>>(Abuf, W1T, bc1, Hbuf, FXD, 80);
    // conv2
    gather_bf<us16, 2><<<NN2 / 4, 256, 0, stream>>>(Hbuf, Hbuf + (size_t)N_NODES * 80, 80, FXD, 96,
                                                    dinv, base, esrc, enorm, Abuf);
    mfma_conv<96><<<dim3(NN2 / 128, 2, 1), 256, 0, stream>>>(Abuf, W2T, bc2, Hbuf, FXD2, 160);
    // conv3
    gather_bf<us16, 3><<<NN2 / 4, 256, 0, stream>>>(Hbuf, Hbuf + (size_t)N_NODES * 160, 160, FXD2, 160,
                                                    dinv, base, esrc, enorm, Abuf);
    mfma_conv<160><<<dim3(NN2 / 128, 4, 1), 256, 0, stream>>>(Abuf, W3T, bc3, Hbuf, FXD4, 320);

    // pool (2048 graphs) + fc
    seg_max_bf<<<dim3(2, 2048, 1), 256, 0, stream>>>(Hbuf, pool, FXD4, 320);
    gemv_rows4<true><<<2048 / 4, 256, 0, stream>>>(pool, Wg1, bg1, nullptr, gb, FXD4, FXD2, FXD2, 0);
    gemv_rows4<false><<<2048 / 4, 256, 0, stream>>>(gb, Wg2, bg2, nullptr, xc, FXD2, OD, 384, OD);

    // ================= final MLP =================
    gemv_rows4<true><<<B_GRAPH / 4, 256, 0, stream>>>(xc, Wf1, bf1, nullptr, f1, 384, 512, 512, 0);
    gemv_rows4<true><<<B_GRAPH / 4, 256, 0, stream>>>(f1, Wf2, bf2, nullptr, f2, 512, OD, OD, 0);
    final_linear2<<<(B_GRAPH * 2 + 255) / 256, 256, 0, stream>>>(f2, Wo, bo, out);
}

// Round 7
// 1086.078 us; speedup vs baseline: 1.2531x; 1.0474x over previous
//
#include <hip/hip_runtime.h>

// Problem constants (fixed by setup_inputs).
constexpr int N_NODES = 40960;
constexpr int E_EDGES = 131072;
constexpr int B_GRAPH = 1024;
constexpr int FXD  = 78;
constexpr int FXD2 = 156;
constexpr int FXD4 = 312;
constexpr int OD   = 128;
constexpr int FXT  = 37261;
constexpr int KP   = 37280;            // FXT padded to mult of 32
constexpr int NPG  = N_NODES / B_GRAPH;
constexpr int NN2  = 2 * N_NODES;      // batched (both drug branches)
constexpr int EE2  = 2 * E_EDGES;

typedef unsigned short us16;
typedef __attribute__((ext_vector_type(8))) short short8;  // 8 bf16
typedef __attribute__((ext_vector_type(4))) float f32x4;

__device__ inline us16 f2bf(float f) {             // fp32 -> bf16 RNE
    unsigned u = __float_as_uint(f);
    return (us16)((u + 0x7FFF + ((u >> 16) & 1)) >> 16);
}
__device__ inline float ldf(const float* p) { return *p; }
__device__ inline float ldf(const us16* p) { return __uint_as_float(((unsigned)*p) << 16); }

// ---------------------------------------------------------------------------
// Cell-layer bf16 MFMA GEMM: cv1[1024x512] += (An[1024xKP] @ BwT^T) * invn[row],
// where invn[row] = 1/max(sqrt(ssq[row]),1e-12) applied in the epilogue
// (per-row scalar is linear -> split-K safe).
// 128x128 tile, BK=32, split-K z=32, register-prefetch pipeline.
// PROVEN (R1): 121.5 us, VGPR 60, no scratch. Prefetch regs are individually
// named scalars — array formulations (even const-indexed) spilled to scratch.
// ---------------------------------------------------------------------------
__global__ __launch_bounds__(256, 2)
void mfma_cell_gemm(const us16* __restrict__ An, const us16* __restrict__ BwT,
                    const float* __restrict__ ssq, float* __restrict__ C)
{
    __shared__ us16 As[128][40];
    __shared__ us16 Bs[128][40];
    const int tid = threadIdx.x;
    const int m0 = blockIdx.x * 128;          // gx = 8
    const int n0 = blockIdx.y * 128;          // gy = 4
    const int S  = KP / 32;                   // 1165
    const int per = (S + gridDim.z - 1) / gridDim.z;
    const int s0 = blockIdx.z * per;
    const int s1 = min(S, s0 + per);

    const int r = tid >> 1;
    const int h = (tid & 1) * 16;

    const us16* Ap = An  + (size_t)(m0 + r) * KP + s0 * 32 + h;
    const us16* Bp = BwT + (size_t)(n0 + r) * KP + s0 * 32 + h;

    const int wave = tid >> 6, lane = tid & 63;
    const int wm = (wave >> 1) * 64, wn = (wave & 1) * 64;
    const int fr = lane & 15, fq = (lane >> 4) * 8;

    f32x4 acc[4][4] = {};
    uint4 pa0, pa1, pb0, pb1;
    if (s0 < s1) {
        pa0 = *(const uint4*)Ap;       pa1 = *(const uint4*)(Ap + 8);
        pb0 = *(const uint4*)Bp;       pb1 = *(const uint4*)(Bp + 8);
    }
    for (int s = s0; s < s1; ++s) {
        __syncthreads();
        *(uint4*)&As[r][h] = pa0;  *(uint4*)&As[r][h + 8] = pa1;
        *(uint4*)&Bs[r][h] = pb0;  *(uint4*)&Bs[r][h + 8] = pb1;
        __syncthreads();
        if (s + 1 < s1) {           // prefetch next iter; latency hides behind MFMA
            Ap += 32; Bp += 32;
            pa0 = *(const uint4*)Ap;  pa1 = *(const uint4*)(Ap + 8);
            pb0 = *(const uint4*)Bp;  pb1 = *(const uint4*)(Bp + 8);
        }
        short8 af[4], bf[4];
#pragma unroll
        for (int t = 0; t < 4; ++t) {
            af[t] = *(const short8*)&As[wm + t * 16 + fr][fq];
            bf[t] = *(const short8*)&Bs[wn + t * 16 + fr][fq];
        }
#pragma unroll
        for (int mt = 0; mt < 4; ++mt)
#pragma unroll
            for (int nt = 0; nt < 4; ++nt)
                acc[mt][nt] = __builtin_amdgcn_mfma_f32_16x16x32_bf16(
                    af[mt], bf[nt], acc[mt][nt], 0, 0, 0);
    }
    // per-row normalization scale (16 rows per lane, const-indexed -> regs)
    float rs[4][4];
#pragma unroll
    for (int mt = 0; mt < 4; ++mt)
#pragma unroll
        for (int reg = 0; reg < 4; ++reg) {
            int row = m0 + wm + mt * 16 + (lane >> 4) * 4 + reg;
            rs[mt][reg] = 1.0f / fmaxf(sqrtf(ssq[row]), 1e-12f);
        }
#pragma unroll
    for (int mt = 0; mt < 4; ++mt)
#pragma unroll
        for (int nt = 0; nt < 4; ++nt)
#pragma unroll
            for (int reg = 0; reg < 4; ++reg) {
                int row = m0 + wm + mt * 16 + (lane >> 4) * 4 + reg;
                int col = n0 + wn + nt * 16 + fr;
                atomicAdd(&C[(size_t)row * 512 + col], acc[mt][nt][reg] * rs[mt][reg]);
            }
}

// Single-pass stream: An[row][k] = bf16(cell[row][k]) (UNnormalized), zero-pad
// to KP; per-block partial sum of fp32 squares atomicAdd'ed into ssq[row].
// No second read, no row barrier — pure streaming convert.
__global__ __launch_bounds__(256)
void convert_cell_bf(const float* __restrict__ cell, us16* __restrict__ An,
                     float* __restrict__ ssq)
{
    const int row = blockIdx.y;
    const int k8 = (blockIdx.x * 256 + threadIdx.x) * 8;
    const float* src = cell + (size_t)row * FXT;
    float ps = 0.f;
    if (k8 < KP) {
        us16 v[8];
#pragma unroll
        for (int j = 0; j < 8; ++j) {
            int k = k8 + j;
            float x = (k < FXT) ? src[k] : 0.0f;
            ps = fmaf(x, x, ps);
            v[j] = f2bf(x);
        }
        *(uint4*)&An[(size_t)row * KP + k8] = *(uint4*)v;
    }
    for (int off = 32; off > 0; off >>= 1) ps += __shfl_down(ps, off, 64);
    __shared__ float sred[4];
    const int lane = threadIdx.x & 63, wv = threadIdx.x >> 6;
    if (lane == 0) sred[wv] = ps;
    __syncthreads();
    if (threadIdx.x == 0)
        atomicAdd(&ssq[row], sred[0] + sred[1] + sred[2] + sred[3]);
}

// WT[n][k] = bf16(W[k][n]), k zero-padded to KPc. 32x32 tiled transpose.
__global__ __launch_bounds__(256)
void convert_wT(const float* __restrict__ W, us16* __restrict__ WT,
                int K, int Nn, int KPc)
{
    __shared__ float tile[32][33];
    const int k0 = blockIdx.x * 32;
    const int n0 = blockIdx.y * 32;
    const int c  = threadIdx.x & 31;
    const int r0 = threadIdx.x >> 5;
#pragma unroll
    for (int p = 0; p < 4; ++p) {
        int k = k0 + r0 + p * 8;
        tile[r0 + p * 8][c] = (k < K && n0 + c < Nn) ? W[(size_t)k * Nn + n0 + c] : 0.0f;
    }
    __syncthreads();
#pragma unroll
    for (int p = 0; p < 4; ++p) {
        int n = n0 + r0 + p * 8;
        if (n < Nn) WT[(size_t)n * KPc + k0 + c] = f2bf(tile[c][r0 + p * 8]);
    }
}

// Small padded weight transpose: WT[n][k] bf16, n in [0,NPr), k in [0,KPc),
// zero-filled outside the real K x Nn extent. Tiny matrices only.
__global__ void convert_wT_small(const float* __restrict__ W, us16* __restrict__ WT,
                                 int K, int Nn, int KPc, int NPr)
{
    int idx = blockIdx.x * 256 + threadIdx.x;
    if (idx >= NPr * KPc) return;
    int n = idx / KPc, k = idx - n * KPc;
    WT[idx] = (n < Nn && k < K) ? f2bf(W[(size_t)k * Nn + n]) : (us16)0;
}

// ---------------------------------------------------------------------------
// Drug-conv bf16 MFMA GEMM: C = relu(A @ WT^T + bias), bf16 out.
// A: [NN2][KA] bf16 (zero-padded K). WT: [NP][KA] bf16 (zero-padded rows).
// Block: 256 thr / 4 waves; BM=128 (wave=32 rows); NTILE=80 (5 n-frags).
// Whole B tile in LDS; A double-buffered per 32-k step.
// ---------------------------------------------------------------------------
template<int KA>
__global__ __launch_bounds__(256, 2)
void mfma_conv(const us16* __restrict__ A, const us16* __restrict__ BT,
               const float* __restrict__ bias, us16* __restrict__ C,
               int Nn, int ldc)
{
    constexpr int KS = KA / 32;
    __shared__ us16 As[2][128][40];
    __shared__ us16 Bs[80][KA + 8];
    const int tid = threadIdx.x;
    const int m0 = blockIdx.x * 128;
    const int n0 = blockIdx.y * 80;

    // B tile (80 x KA), read-once (hot in L2 across blocks)
    for (int idx = tid; idx < 80 * (KA / 8); idx += 256) {
        int nr = idx / (KA / 8), c8 = (idx - nr * (KA / 8)) * 8;
        *(uint4*)&Bs[nr][c8] = *(const uint4*)&BT[(size_t)(n0 + nr) * KA + c8];
    }

    const int r = tid >> 1, h = (tid & 1) * 16;
    const us16* Ap = A + (size_t)(m0 + r) * KA + h;
    *(uint4*)&As[0][r][h]     = *(const uint4*)Ap;
    *(uint4*)&As[0][r][h + 8] = *(const uint4*)(Ap + 8);
    __syncthreads();

    const int wave = tid >> 6, lane = tid & 63;
    const int wm = wave * 32;
    const int fr = lane & 15, fq = (lane >> 4) * 8;

    f32x4 acc[2][5] = {};
#pragma unroll
    for (int s = 0; s < KS; ++s) {
        const int cb = s & 1;
        if (s + 1 < KS) {                    // prefetch next chunk into other buffer
            uint4 t0 = *(const uint4*)(Ap + 32);
            uint4 t1 = *(const uint4*)(Ap + 40);
            Ap += 32;
            *(uint4*)&As[cb ^ 1][r][h]     = t0;
            *(uint4*)&As[cb ^ 1][r][h + 8] = t1;
        }
        short8 af[2], bf[5];
#pragma unroll
        for (int mt = 0; mt < 2; ++mt)
            af[mt] = *(const short8*)&As[cb][wm + mt * 16 + fr][fq];
#pragma unroll
        for (int nf = 0; nf < 5; ++nf)
            bf[nf] = *(const short8*)&Bs[nf * 16 + fr][s * 32 + fq];
#pragma unroll
        for (int mt = 0; mt < 2; ++mt)
#pragma unroll
            for (int nf = 0; nf < 5; ++nf)
                acc[mt][nf] = __builtin_amdgcn_mfma_f32_16x16x32_bf16(
                    af[mt], bf[nf], acc[mt][nf], 0, 0, 0);
        __syncthreads();
    }

#pragma unroll
    for (int mt = 0; mt < 2; ++mt)
#pragma unroll
        for (int nf = 0; nf < 5; ++nf) {
            const int col = n0 + nf * 16 + fr;
            if (col < Nn) {
                const float bv = bias[col];
#pragma unroll
                for (int reg = 0; reg < 4; ++reg) {
                    int row = m0 + wm + mt * 16 + (lane >> 4) * 4 + reg;
                    C[(size_t)row * ldc + col] = f2bf(fmaxf(acc[mt][nf][reg] + bv, 0.0f));
                }
            }
        }
}

// ---------------------------------------------------------------------------
// Batched (both graphs) edge sort + gather aggregation.
// ---------------------------------------------------------------------------
__global__ void deg_count_b(const int* __restrict__ ei1, const int* __restrict__ ei2,
                            int* cnt) {
    int i = blockIdx.x * blockDim.x + threadIdx.x;
    if (i >= EE2) return;
    int d = (i < E_EDGES) ? ei1[E_EDGES + i] : ei2[E_EDGES + (i - E_EDGES)] + N_NODES;
    atomicAdd(&cnt[d], 1);
}

__global__ __launch_bounds__(512)
void scan1(const int* __restrict__ cnt, int* base, int* aux, float* dinv) {
    __shared__ int s[512];
    const int tid = threadIdx.x;
    const int i = blockIdx.x * 512 + tid;
    int v = cnt[i];
    dinv[i] = rsqrtf((float)(v + 1));
    s[tid] = v;
    __syncthreads();
    for (int off = 1; off < 512; off <<= 1) {
        int t = (tid >= off) ? s[tid - off] : 0;
        __syncthreads();
        s[tid] += t;
        __syncthreads();
    }
    base[i] = s[tid] - v;
    if (tid == 511) aux[blockIdx.x] = s[511];
}

__global__ void scan2(int* aux, int nblk) {
    __shared__ int s[256];
    const int tid = threadIdx.x;
    int v = (tid < nblk) ? aux[tid] : 0;
    s[tid] = v;
    __syncthreads();
    for (int off = 1; off < 256; off <<= 1) {
        int t = (tid >= off) ? s[tid - off] : 0;
        __syncthreads();
        s[tid] += t;
        __syncthreads();
    }
    if (tid < nblk) aux[tid] = s[tid] - v;
}

__global__ __launch_bounds__(512)
void scan3(int* base, const int* __restrict__ aux) {
    int i = blockIdx.x * 512 + threadIdx.x;
    base[i] += aux[blockIdx.x];
    if (i == 0) base[NN2] = EE2;
}

__global__ void place_edges_b(const int* __restrict__ ei1, const int* __restrict__ ei2,
                              const float* __restrict__ dinv, const int* __restrict__ base,
                              int* cur, int* __restrict__ esrc, float* __restrict__ enorm) {
    int e = blockIdx.x * blockDim.x + threadIdx.x;
    if (e >= EE2) return;
    int s, d;
    if (e < E_EDGES) { s = ei1[e];            d = ei1[E_EDGES + e]; }
    else             { s = ei2[e - E_EDGES] + N_NODES;
                       d = ei2[E_EDGES + (e - E_EDGES)] + N_NODES; }
    int p = base[d] + atomicAdd(&cur[d], 1);
    esrc[p]  = s;
    enorm[p] = dinv[s] * dinv[d];
}

// out[row][0:kaout] = bf16( sum_edges h[src]*norm + h[row]*dinv^2 ), zero pad.
template<typename Tin, int CH>
__global__ __launch_bounds__(256)
void gather_bf(const Tin* __restrict__ hA, const Tin* __restrict__ hB, int st, int fi, int kaout,
               const float* __restrict__ dinv, const int* __restrict__ base,
               const int* __restrict__ esrc, const float* __restrict__ enorm,
               us16* __restrict__ out)
{
    const int row  = blockIdx.x * 4 + (threadIdx.x >> 6);
    const int lane = threadIdx.x & 63;
    const float d  = dinv[row];
    const float d2 = d * d;
    const Tin* hr = (row < N_NODES) ? hA + (size_t)row * st
                                    : hB + (size_t)(row - N_NODES) * st;
    float acc[CH];
#pragma unroll
    for (int c = 0; c < CH; ++c) {
        int f = lane + 64 * c;
        acc[c] = (f < fi) ? ldf(hr + f) * d2 : 0.0f;
    }
    const int b0 = base[row], b1 = base[row + 1];
    for (int j = b0; j < b1; ++j) {
        const int s = esrc[j];
        const float w = enorm[j];
        const Tin* hs = (s < N_NODES) ? hA + (size_t)s * st
                                      : hB + (size_t)(s - N_NODES) * st;
#pragma unroll
        for (int c = 0; c < CH; ++c) {
            int f = lane + 64 * c;
            if (f < fi) acc[c] = fmaf(ldf(hs + f), w, acc[c]);
        }
    }
    us16* orow = out + (size_t)row * kaout;
#pragma unroll
    for (int c = 0; c < CH; ++c) {
        int f = lane + 64 * c;
        if (f < kaout) orow[f] = f2bf(acc[c]);   // acc==0 for f>=fi -> zero pad
    }
}

// ---------------------------------------------------------------------------
__global__ void seg_max_bf(const us16* __restrict__ x, float* __restrict__ out,
                           int fo, int ld) {
    int f = blockIdx.x * blockDim.x + threadIdx.x;
    int g = blockIdx.y;
    if (f >= fo) return;
    const us16* xp = x + (size_t)g * NPG * ld + f;
    float v = -1e30f;
#pragma unroll 4
    for (int j = 0; j < NPG; ++j) v = fmaxf(v, ldf(xp + (size_t)j * ld));
    out[(size_t)g * fo + f] = v;
}

// C = act(A@B + bias). pre != null (K pow2): relu(A+pre) fused on load.
// half_off == 0: plain row addressing (rows can exceed 1024).
// half_off != 0: rows >= 1024 map to row-1024, column offset half_off.
template<bool RELU>
__global__ __launch_bounds__(256)
void gemv_rows4(const float* __restrict__ A, const float* __restrict__ B,
                const float* __restrict__ bias, const float* __restrict__ pre,
                float* __restrict__ C, int K, int N, int ldc, int half_off)
{
    __shared__ float As[4 * 512];
    const int tid = threadIdx.x;
    const int r0 = blockIdx.x * 4;
    if (pre) {
        for (int i = tid; i < 4 * K; i += 256)
            As[i] = fmaxf(A[(size_t)r0 * K + i] + pre[i & (K - 1)], 0.0f);
    } else {
        for (int i = tid; i < 4 * K; i += 256) As[i] = A[(size_t)r0 * K + i];
    }
    __syncthreads();
    float* Cb;
    if (half_off != 0)
        Cb = C + (size_t)(r0 & 1023) * ldc + ((r0 >= 1024) ? half_off : 0);
    else
        Cb = C + (size_t)r0 * ldc;
    for (int n = tid; n < N; n += 256) {
        float b0 = bias[n];
        float a0 = b0, a1 = b0, a2 = b0, a3 = b0;
        const float* Bp = B + n;
        for (int k = 0; k < K; ++k) {
            float b = Bp[(size_t)k * N];
            a0 = fmaf(As[k], b, a0);
            a1 = fmaf(As[K + k], b, a1);
            a2 = fmaf(As[2 * K + k], b, a2);
            a3 = fmaf(As[3 * K + k], b, a3);
        }
        if (RELU) { a0 = fmaxf(a0, 0.f); a1 = fmaxf(a1, 0.f); a2 = fmaxf(a2, 0.f); a3 = fmaxf(a3, 0.f); }
        Cb[0 * ldc + n] = a0;
        Cb[1 * ldc + n] = a1;
        Cb[2 * ldc + n] = a2;
        Cb[3 * ldc + n] = a3;
    }
}

__global__ void final_linear2(const float* __restrict__ x, const float* __restrict__ W,
                              const float* __restrict__ b, float* __restrict__ out) {
    int i = blockIdx.x * blockDim.x + threadIdx.x;
    if (i >= B_GRAPH * 2) return;
    int row = i >> 1, o = i & 1;
    const float* xr = x + (size_t)row * 128;
    float acc = b[o];
    for (int k = 0; k < 128; ++k) acc = fmaf(xr[k], W[k * 2 + o], acc);
    out[i] = acc;
}

// ---------------------------------------------------------------------------
extern "C" void kernel_launch(void* const* d_in, const int* in_sizes, int n_in,
                              void* d_out, int out_size, void* d_ws, size_t ws_size,
                              hipStream_t stream) {
    (void)in_sizes; (void)n_in; (void)out_size; (void)ws_size;
    const float* x1   = (const float*)d_in[0];
    const int*   ei1  = (const int*)d_in[1];
    const float* x2   = (const float*)d_in[3];
    const int*   ei2  = (const int*)d_in[4];
    const float* cell = (const float*)d_in[6];
    const float* Wc1 = (const float*)d_in[7];  const float* bc1 = (const float*)d_in[8];
    const float* Wc2 = (const float*)d_in[9];  const float* bc2 = (const float*)d_in[10];
    const float* Wc3 = (const float*)d_in[11]; const float* bc3 = (const float*)d_in[12];
    const float* Wg1 = (const float*)d_in[13]; const float* bg1 = (const float*)d_in[14];
    const float* Wg2 = (const float*)d_in[15]; const float* bg2 = (const float*)d_in[16];
    const float* Wr1 = (const float*)d_in[17]; const float* br1 = (const float*)d_in[18];
    const float* Wr2 = (const float*)d_in[19]; const float* br2 = (const float*)d_in[20];
    const float* Wr3 = (const float*)d_in[21]; const float* br3 = (const float*)d_in[22];
    const float* Wf1 = (const float*)d_in[23]; const float* bf1 = (const float*)d_in[24];
    const float* Wf2 = (const float*)d_in[25]; const float* bf2 = (const float*)d_in[26];
    const float* Wo  = (const float*)d_in[27]; const float* bo  = (const float*)d_in[28];
    float* out = (float*)d_out;

    // ---- workspace: persistent (~11.5 MB) + union region ----
    float* ws = (float*)d_ws;
    float* xc   = ws;  ws += (size_t)B_GRAPH * 384;
    float* ssq  = ws;  ws += B_GRAPH;      // per-row sum of squares (cell)
    float* cv1  = ws;  ws += (size_t)B_GRAPH * 512;
    float* cv2  = ws;  ws += (size_t)B_GRAPH * 256;
    float* f1   = ws;  ws += (size_t)B_GRAPH * 512;
    float* f2   = ws;  ws += (size_t)B_GRAPH * 128;
    float* dinv = ws;  ws += NN2;
    float* pool = ws;  ws += (size_t)2048 * FXD4;
    float* gb   = ws;  ws += (size_t)2048 * FXD2;

    // union A: cell phase bf16 buffers (1536 x KP bf16 = 114.5 MB)
    us16* An  = (us16*)ws;
    us16* BwT = An + (size_t)B_GRAPH * KP;

    // union B: branch phase (used strictly after mfma_cell_gemm; ~81 MB)
    us16* Abuf = (us16*)ws;                        // gather out, NN2 x <=160 bf16
    us16* Hbuf = Abuf + (size_t)NN2 * 160;         // conv out,  NN2 x <=320 bf16
    us16* W1T  = Hbuf + (size_t)NN2 * 320;         // 80  x 96  (16B-aligned)
    us16* W2T  = W1T + 80 * 96;                    // 160 x 96
    us16* W3T  = W2T + 160 * 96;                   // 320 x 160
    float* enorm = (float*)(W3T + 320 * 160);
    int* cnt  = (int*)(enorm + EE2);
    int* cur  = cnt + NN2;
    int* base = cur + NN2;
    int* aux  = base + NN2 + 1;
    int* esrc = aux + 256;

    // ================= cell branch (bf16 MFMA) =================
    hipMemsetAsync(ssq, 0, (size_t)B_GRAPH * sizeof(float), stream);
    convert_cell_bf<<<dim3((KP / 8 + 255) / 256, B_GRAPH, 1), 256, 0, stream>>>(cell, An, ssq);
    convert_wT<<<dim3(KP / 32, 512 / 32, 1), 256, 0, stream>>>(Wr1, BwT, FXT, 512, KP);
    hipMemsetAsync(cv1, 0, (size_t)B_GRAPH * 512 * sizeof(float), stream);
    mfma_cell_gemm<<<dim3(8, 4, 32), 256, 0, stream>>>(An, BwT, ssq, cv1);
    // bias+relu on cv1 fused into the next gemv's A load (pre=br1, K=512 pow2)
    gemv_rows4<true><<<B_GRAPH / 4, 256, 0, stream>>>(cv1, Wr2, br2, br1, cv2, 512, 256, 256, 0);
    gemv_rows4<false><<<B_GRAPH / 4, 256, 0, stream>>>(cv2, Wr3, br3, nullptr, xc + 256, 256, OD, 384, 0);

    // ================= drug branches (batched, bf16 MFMA convs) =================
    hipMemsetAsync(cnt, 0, (size_t)2 * NN2 * sizeof(int), stream);   // cnt + cur
    deg_count_b<<<(EE2 + 255) / 256, 256, 0, stream>>>(ei1, ei2, cnt);
    scan1<<<NN2 / 512, 512, 0, stream>>>(cnt, base, aux, dinv);
    scan2<<<1, 256, 0, stream>>>(aux, NN2 / 512);
    scan3<<<NN2 / 512, 512, 0, stream>>>(base, aux);
    place_edges_b<<<(EE2 + 255) / 256, 256, 0, stream>>>(ei1, ei2, dinv, base, cur, esrc, enorm);

    // conv weights -> padded bf16 WT[n][k] (tiny; after cell phase frees union)
    convert_wT_small<<<(80 * 96 + 255) / 256, 256, 0, stream>>>(Wc1, W1T, FXD, FXD, 96, 80);
    convert_wT_small<<<(160 * 96 + 255) / 256, 256, 0, stream>>>(Wc2, W2T, FXD, FXD2, 96, 160);
    convert_wT_small<<<(320 * 160 + 255) / 256, 256, 0, stream>>>(Wc3, W3T, FXD2, FXD4, 160, 320);

    // conv1: gather(x) -> Abuf[96]; relu(Abuf@Wc1+bc1) -> Hbuf[80]
    gather_bf<float, 2><<<NN2 / 4, 256, 0, stream>>>(x1, x2, FXD, FXD, 96,
                                                     dinv, base, esrc, enorm, Abuf);
    mfma_conv<96><<<dim3(NN2 / 128, 1, 1), 256, 0, stream>>>(Abuf, W1T, bc1, Hbuf, FXD, 80);
    // conv2
    gather_bf<us16, 2><<<NN2 / 4, 256, 0, stream>>>(Hbuf, Hbuf + (size_t)N_NODES * 80, 80, FXD, 96,
                                                    dinv, base, esrc, enorm, Abuf);
    mfma_conv<96><<<dim3(NN2 / 128, 2, 1), 256, 0, stream>>>(Abuf, W2T, bc2, Hbuf, FXD2, 160);
    // conv3
    gather_bf<us16, 3><<<NN2 / 4, 256, 0, stream>>>(Hbuf, Hbuf + (size_t)N_NODES * 160, 160, FXD2, 160,
                                                    dinv, base, esrc, enorm, Abuf);
    mfma_conv<160><<<dim3(NN2 / 128, 4, 1), 256, 0, stream>>>(Abuf, W3T, bc3, Hbuf, FXD4, 320);

    // pool (2048 graphs) + fc
    seg_max_bf<<<dim3(2, 2048, 1), 256, 0, stream>>>(Hbuf, pool, FXD4, 320);
    gemv_rows4<true><<<2048 / 4, 256, 0, stream>>>(pool, Wg1, bg1, nullptr, gb, FXD4, FXD2, FXD2, 0);
    gemv_rows4<false><<<2048 / 4, 256, 0, stream>>>(gb, Wg2, bg2, nullptr, xc, FXD2, OD, 384, OD);

    // ================= final MLP =================
    gemv_rows4<true><<<B_GRAPH / 4, 256, 0, stream>>>(xc, Wf1, bf1, nullptr, f1, 384, 512, 512, 0);
    gemv_rows4<true><<<B_GRAPH / 4, 256, 0, stream>>>(f1, Wf2, bf2, nullptr, f2, 512, OD, OD, 0);
    final_linear2<<<(B_GRAPH * 2 + 255) / 256, 256, 0, stream>>>(f2, Wo, bo, out);
}

// Round 8
// 1047.992 us; speedup vs baseline: 1.2987x; 1.0363x over previous
//
#include <hip/hip_runtime.h>

// Problem constants (fixed by setup_inputs).
constexpr int N_NODES = 40960;
constexpr int E_EDGES = 131072;
constexpr int B_GRAPH = 1024;
constexpr int FXD  = 78;
constexpr int FXD2 = 156;
constexpr int FXD4 = 312;
constexpr int OD   = 128;
constexpr int FXT  = 37261;
constexpr int KP   = 37312;            // FXT padded to mult of 64 (BK=64 cell GEMM)
constexpr int NPG  = N_NODES / B_GRAPH;
constexpr int NN2  = 2 * N_NODES;      // batched (both drug branches)
constexpr int EE2  = 2 * E_EDGES;

typedef unsigned short us16;
typedef __attribute__((ext_vector_type(8))) short short8;  // 8 bf16
typedef __attribute__((ext_vector_type(4))) float f32x4;

__device__ inline us16 f2bf(float f) {             // fp32 -> bf16 RNE
    unsigned u = __float_as_uint(f);
    return (us16)((u + 0x7FFF + ((u >> 16) & 1)) >> 16);
}
__device__ inline float ldf(const float* p) { return *p; }
__device__ inline float ldf(const us16* p) { return __uint_as_float(((unsigned)*p) << 16); }

// ---------------------------------------------------------------------------
// Cell-layer bf16 MFMA GEMM: cv1[1024x512] += (An[1024xKP] @ BwT^T) * invn[row]
// invn[row] = 1/max(sqrt(ssq[row]),1e-12) applied in epilogue (split-K safe).
// BK=64, split-K z=16, double-buffered LDS filled via async global_load_lds
// (width=16, no VGPR staging -> no spill risk). One barrier per K-step.
// Swizzle is both-sides (rule #21): LDS dest linear, SOURCE chunk permuted
// (l&7)^(l>>3); reads apply chunk ^ (lane&7). ~2-way LDS conflicts (free).
// ---------------------------------------------------------------------------
#define CG_STAGE(buf, s)                                                       \
    {                                                                          \
        _Pragma("unroll")                                                      \
        for (int i = 0; i < 4; ++i) {                                          \
            __builtin_amdgcn_global_load_lds(                                  \
                (const __attribute__((address_space(1))) unsigned*)            \
                    (Ag + (size_t)i * 8 * KP + (size_t)(s) * 64),              \
                (__attribute__((address_space(3))) unsigned*)                  \
                    &As[buf][wave * 32 + i * 8][0], 16, 0, 0);                 \
            __builtin_amdgcn_global_load_lds(                                  \
                (const __attribute__((address_space(1))) unsigned*)            \
                    (Bg + (size_t)i * 8 * KP + (size_t)(s) * 64),              \
                (__attribute__((address_space(3))) unsigned*)                  \
                    &Bs[buf][wave * 32 + i * 8][0], 16, 0, 0);                 \
        }                                                                      \
    }

__global__ __launch_bounds__(256, 2)
void mfma_cell_gemm(const us16* __restrict__ An, const us16* __restrict__ BwT,
                    const float* __restrict__ ssq, float* __restrict__ C)
{
    __shared__ us16 As[2][128][64];     // 32 KB
    __shared__ us16 Bs[2][128][64];     // 32 KB
    const int tid = threadIdx.x;
    const int m0 = blockIdx.x * 128;          // gx = 8
    const int n0 = blockIdx.y * 128;          // gy = 4
    const int S  = KP / 64;                   // 583
    const int per = (S + gridDim.z - 1) / gridDim.z;
    const int s0 = blockIdx.z * per;
    const int s1 = min(S, s0 + per);

    const int wave = tid >> 6, lane = tid & 63;
    // staging: wave w instr i fills LDS rows [w*32+i*8, +8), lane l -> row +l>>3,
    // chunk slot l&7; source chunk = (l&7)^(l>>3) so slot c holds chunk c^(row&7)
    const int srow = lane >> 3;
    const int swz  = (lane & 7) ^ srow;
    const us16* Ag = An  + (size_t)(m0 + wave * 32 + srow) * KP + swz * 8;
    const us16* Bg = BwT + (size_t)(n0 + wave * 32 + srow) * KP + swz * 8;

    const int wm = (wave >> 1) * 64, wn = (wave & 1) * 64;
    const int fr = lane & 15, fq8 = (lane >> 4);   // fragment chunk within substep
    const int sx = lane & 7;                       // read-side xor = row&7

    f32x4 acc[4][4] = {};

    CG_STAGE(0, s0)
    __syncthreads();
    int cb = 0;
    for (int s = s0; s < s1; ++s) {
        if (s + 1 < s1) CG_STAGE(cb ^ 1, s + 1)    // async; lands by next barrier
#pragma unroll
        for (int ks = 0; ks < 2; ++ks) {           // two K=32 substeps
            const int c = ks * 4 + fq8;            // logical chunk 0..7
            short8 af[4], bf[4];
#pragma unroll
            for (int t = 0; t < 4; ++t) {
                af[t] = *(const short8*)&As[cb][wm + t * 16 + fr][(c ^ sx) * 8];
                bf[t] = *(const short8*)&Bs[cb][wn + t * 16 + fr][(c ^ sx) * 8];
            }
#pragma unroll
            for (int mt = 0; mt < 4; ++mt)
#pragma unroll
                for (int nt = 0; nt < 4; ++nt)
                    acc[mt][nt] = __builtin_amdgcn_mfma_f32_16x16x32_bf16(
                        af[mt], bf[nt], acc[mt][nt], 0, 0, 0);
        }
        __syncthreads();                           // drains vmcnt -> next buf ready
        cb ^= 1;
    }

    // per-row normalization scale (const-indexed -> regs)
    float rs[4][4];
#pragma unroll
    for (int mt = 0; mt < 4; ++mt)
#pragma unroll
        for (int reg = 0; reg < 4; ++reg) {
            int row = m0 + wm + mt * 16 + (lane >> 4) * 4 + reg;
            rs[mt][reg] = 1.0f / fmaxf(sqrtf(ssq[row]), 1e-12f);
        }
#pragma unroll
    for (int mt = 0; mt < 4; ++mt)
#pragma unroll
        for (int nt = 0; nt < 4; ++nt)
#pragma unroll
            for (int reg = 0; reg < 4; ++reg) {
                int row = m0 + wm + mt * 16 + (lane >> 4) * 4 + reg;
                int col = n0 + wn + nt * 16 + fr;
                atomicAdd(&C[(size_t)row * 512 + col], acc[mt][nt][reg] * rs[mt][reg]);
            }
}

// Single-pass stream: An[row][k] = bf16(cell[row][k]) (UNnormalized), zero-pad
// to KP; per-block partial sum of fp32 squares atomicAdd'ed into ssq[row].
__global__ __launch_bounds__(256)
void convert_cell_bf(const float* __restrict__ cell, us16* __restrict__ An,
                     float* __restrict__ ssq)
{
    const int row = blockIdx.y;
    const int k8 = (blockIdx.x * 256 + threadIdx.x) * 8;
    const float* src = cell + (size_t)row * FXT;
    float ps = 0.f;
    if (k8 < KP) {
        us16 v[8];
#pragma unroll
        for (int j = 0; j < 8; ++j) {
            int k = k8 + j;
            float x = (k < FXT) ? src[k] : 0.0f;
            ps = fmaf(x, x, ps);
            v[j] = f2bf(x);
        }
        *(uint4*)&An[(size_t)row * KP + k8] = *(uint4*)v;
    }
    for (int off = 32; off > 0; off >>= 1) ps += __shfl_down(ps, off, 64);
    __shared__ float sred[4];
    const int lane = threadIdx.x & 63, wv = threadIdx.x >> 6;
    if (lane == 0) sred[wv] = ps;
    __syncthreads();
    if (threadIdx.x == 0)
        atomicAdd(&ssq[row], sred[0] + sred[1] + sred[2] + sred[3]);
}

// WT[n][k] = bf16(W[k][n]), k zero-padded to KPc. 32x32 tiled transpose.
__global__ __launch_bounds__(256)
void convert_wT(const float* __restrict__ W, us16* __restrict__ WT,
                int K, int Nn, int KPc)
{
    __shared__ float tile[32][33];
    const int k0 = blockIdx.x * 32;
    const int n0 = blockIdx.y * 32;
    const int c  = threadIdx.x & 31;
    const int r0 = threadIdx.x >> 5;
#pragma unroll
    for (int p = 0; p < 4; ++p) {
        int k = k0 + r0 + p * 8;
        tile[r0 + p * 8][c] = (k < K && n0 + c < Nn) ? W[(size_t)k * Nn + n0 + c] : 0.0f;
    }
    __syncthreads();
#pragma unroll
    for (int p = 0; p < 4; ++p) {
        int n = n0 + r0 + p * 8;
        if (n < Nn) WT[(size_t)n * KPc + k0 + c] = f2bf(tile[c][r0 + p * 8]);
    }
}

// Small padded weight transpose: WT[n][k] bf16, n in [0,NPr), k in [0,KPc),
// zero-filled outside the real K x Nn extent. Tiny matrices only.
__global__ void convert_wT_small(const float* __restrict__ W, us16* __restrict__ WT,
                                 int K, int Nn, int KPc, int NPr)
{
    int idx = blockIdx.x * 256 + threadIdx.x;
    if (idx >= NPr * KPc) return;
    int n = idx / KPc, k = idx - n * KPc;
    WT[idx] = (n < Nn && k < K) ? f2bf(W[(size_t)k * Nn + n]) : (us16)0;
}

// ---------------------------------------------------------------------------
// Drug-conv bf16 MFMA GEMM: C = relu(A @ WT^T + bias), bf16 out.
// A: [NN2][KA] bf16 (zero-padded K). WT: [NP][KA] bf16 (zero-padded rows).
// Block: 256 thr / 4 waves; BM=128 (wave=32 rows); NTILE=80 (5 n-frags).
// Whole B tile in LDS; A double-buffered per 32-k step.
// ---------------------------------------------------------------------------
template<int KA>
__global__ __launch_bounds__(256, 2)
void mfma_conv(const us16* __restrict__ A, const us16* __restrict__ BT,
               const float* __restrict__ bias, us16* __restrict__ C,
               int Nn, int ldc)
{
    constexpr int KS = KA / 32;
    __shared__ us16 As[2][128][40];
    __shared__ us16 Bs[80][KA + 8];
    const int tid = threadIdx.x;
    const int m0 = blockIdx.x * 128;
    const int n0 = blockIdx.y * 80;

    // B tile (80 x KA), read-once (hot in L2 across blocks)
    for (int idx = tid; idx < 80 * (KA / 8); idx += 256) {
        int nr = idx / (KA / 8), c8 = (idx - nr * (KA / 8)) * 8;
        *(uint4*)&Bs[nr][c8] = *(const uint4*)&BT[(size_t)(n0 + nr) * KA + c8];
    }

    const int r = tid >> 1, h = (tid & 1) * 16;
    const us16* Ap = A + (size_t)(m0 + r) * KA + h;
    *(uint4*)&As[0][r][h]     = *(const uint4*)Ap;
    *(uint4*)&As[0][r][h + 8] = *(const uint4*)(Ap + 8);
    __syncthreads();

    const int wave = tid >> 6, lane = tid & 63;
    const int wm = wave * 32;
    const int fr = lane & 15, fq = (lane >> 4) * 8;

    f32x4 acc[2][5] = {};
#pragma unroll
    for (int s = 0; s < KS; ++s) {
        const int cb = s & 1;
        if (s + 1 < KS) {                    // prefetch next chunk into other buffer
            uint4 t0 = *(const uint4*)(Ap + 32);
            uint4 t1 = *(const uint4*)(Ap + 40);
            Ap += 32;
            *(uint4*)&As[cb ^ 1][r][h]     = t0;
            *(uint4*)&As[cb ^ 1][r][h + 8] = t1;
        }
        short8 af[2], bf[5];
#pragma unroll
        for (int mt = 0; mt < 2; ++mt)
            af[mt] = *(const short8*)&As[cb][wm + mt * 16 + fr][fq];
#pragma unroll
        for (int nf = 0; nf < 5; ++nf)
            bf[nf] = *(const short8*)&Bs[nf * 16 + fr][s * 32 + fq];
#pragma unroll
        for (int mt = 0; mt < 2; ++mt)
#pragma unroll
            for (int nf = 0; nf < 5; ++nf)
                acc[mt][nf] = __builtin_amdgcn_mfma_f32_16x16x32_bf16(
                    af[mt], bf[nf], acc[mt][nf], 0, 0, 0);
        __syncthreads();
    }

#pragma unroll
    for (int mt = 0; mt < 2; ++mt)
#pragma unroll
        for (int nf = 0; nf < 5; ++nf) {
            const int col = n0 + nf * 16 + fr;
            if (col < Nn) {
                const float bv = bias[col];
#pragma unroll
                for (int reg = 0; reg < 4; ++reg) {
                    int row = m0 + wm + mt * 16 + (lane >> 4) * 4 + reg;
                    C[(size_t)row * ldc + col] = f2bf(fmaxf(acc[mt][nf][reg] + bv, 0.0f));
                }
            }
        }
}

// ---------------------------------------------------------------------------
// Batched (both graphs) edge sort + gather aggregation.
// ---------------------------------------------------------------------------
__global__ void deg_count_b(const int* __restrict__ ei1, const int* __restrict__ ei2,
                            int* cnt) {
    int i = blockIdx.x * blockDim.x + threadIdx.x;
    if (i >= EE2) return;
    int d = (i < E_EDGES) ? ei1[E_EDGES + i] : ei2[E_EDGES + (i - E_EDGES)] + N_NODES;
    atomicAdd(&cnt[d], 1);
}

__global__ __launch_bounds__(512)
void scan1(const int* __restrict__ cnt, int* base, int* aux, float* dinv) {
    __shared__ int s[512];
    const int tid = threadIdx.x;
    const int i = blockIdx.x * 512 + tid;
    int v = cnt[i];
    dinv[i] = rsqrtf((float)(v + 1));
    s[tid] = v;
    __syncthreads();
    for (int off = 1; off < 512; off <<= 1) {
        int t = (tid >= off) ? s[tid - off] : 0;
        __syncthreads();
        s[tid] += t;
        __syncthreads();
    }
    base[i] = s[tid] - v;
    if (tid == 511) aux[blockIdx.x] = s[511];
}

__global__ void scan2(int* aux, int nblk) {
    __shared__ int s[256];
    const int tid = threadIdx.x;
    int v = (tid < nblk) ? aux[tid] : 0;
    s[tid] = v;
    __syncthreads();
    for (int off = 1; off < 256; off <<= 1) {
        int t = (tid >= off) ? s[tid - off] : 0;
        __syncthreads();
        s[tid] += t;
        __syncthreads();
    }
    if (tid < nblk) aux[tid] = s[tid] - v;
}

__global__ __launch_bounds__(512)
void scan3(int* base, const int* __restrict__ aux) {
    int i = blockIdx.x * 512 + threadIdx.x;
    base[i] += aux[blockIdx.x];
    if (i == 0) base[NN2] = EE2;
}

__global__ void place_edges_b(const int* __restrict__ ei1, const int* __restrict__ ei2,
                              const float* __restrict__ dinv, const int* __restrict__ base,
                              int* cur, int* __restrict__ esrc, float* __restrict__ enorm) {
    int e = blockIdx.x * blockDim.x + threadIdx.x;
    if (e >= EE2) return;
    int s, d;
    if (e < E_EDGES) { s = ei1[e];            d = ei1[E_EDGES + e]; }
    else             { s = ei2[e - E_EDGES] + N_NODES;
                       d = ei2[E_EDGES + (e - E_EDGES)] + N_NODES; }
    int p = base[d] + atomicAdd(&cur[d], 1);
    esrc[p]  = s;
    enorm[p] = dinv[s] * dinv[d];
}

// out[row][0:kaout] = bf16( sum_edges h[src]*norm + h[row]*dinv^2 ), zero pad.
template<typename Tin, int CH>
__global__ __launch_bounds__(256)
void gather_bf(const Tin* __restrict__ hA, const Tin* __restrict__ hB, int st, int fi, int kaout,
               const float* __restrict__ dinv, const int* __restrict__ base,
               const int* __restrict__ esrc, const float* __restrict__ enorm,
               us16* __restrict__ out)
{
    const int row  = blockIdx.x * 4 + (threadIdx.x >> 6);
    const int lane = threadIdx.x & 63;
    const float d  = dinv[row];
    const float d2 = d * d;
    const Tin* hr = (row < N_NODES) ? hA + (size_t)row * st
                                    : hB + (size_t)(row - N_NODES) * st;
    float acc[CH];
#pragma unroll
    for (int c = 0; c < CH; ++c) {
        int f = lane + 64 * c;
        acc[c] = (f < fi) ? ldf(hr + f) * d2 : 0.0f;
    }
    const int b0 = base[row], b1 = base[row + 1];
    for (int j = b0; j < b1; ++j) {
        const int s = esrc[j];
        const float w = enorm[j];
        const Tin* hs = (s < N_NODES) ? hA + (size_t)s * st
                                      : hB + (size_t)(s - N_NODES) * st;
#pragma unroll
        for (int c = 0; c < CH; ++c) {
            int f = lane + 64 * c;
            if (f < fi) acc[c] = fmaf(ldf(hs + f), w, acc[c]);
        }
    }
    us16* orow = out + (size_t)row * kaout;
#pragma unroll
    for (int c = 0; c < CH; ++c) {
        int f = lane + 64 * c;
        if (f < kaout) orow[f] = f2bf(acc[c]);   // acc==0 for f>=fi -> zero pad
    }
}

// ---------------------------------------------------------------------------
__global__ void seg_max_bf(const us16* __restrict__ x, float* __restrict__ out,
                           int fo, int ld) {
    int f = blockIdx.x * blockDim.x + threadIdx.x;
    int g = blockIdx.y;
    if (f >= fo) return;
    const us16* xp = x + (size_t)g * NPG * ld + f;
    float v = -1e30f;
#pragma unroll 4
    for (int j = 0; j < NPG; ++j) v = fmaxf(v, ldf(xp + (size_t)j * ld));
    out[(size_t)g * fo + f] = v;
}

// C = act(A@B + bias). pre != null (K pow2): relu(A+pre) fused on load.
// half_off == 0: plain row addressing (rows can exceed 1024).
// half_off != 0: rows >= 1024 map to row-1024, column offset half_off.
template<bool RELU>
__global__ __launch_bounds__(256)
void gemv_rows4(const float* __restrict__ A, const float* __restrict__ B,
                const float* __restrict__ bias, const float* __restrict__ pre,
                float* __restrict__ C, int K, int N, int ldc, int half_off)
{
    __shared__ float As[4 * 512];
    const int tid = threadIdx.x;
    const int r0 = blockIdx.x * 4;
    if (pre) {
        for (int i = tid; i < 4 * K; i += 256)
            As[i] = fmaxf(A[(size_t)r0 * K + i] + pre[i & (K - 1)], 0.0f);
    } else {
        for (int i = tid; i < 4 * K; i += 256) As[i] = A[(size_t)r0 * K + i];
    }
    __syncthreads();
    float* Cb;
    if (half_off != 0)
        Cb = C + (size_t)(r0 & 1023) * ldc + ((r0 >= 1024) ? half_off : 0);
    else
        Cb = C + (size_t)r0 * ldc;
    for (int n = tid; n < N; n += 256) {
        float b0 = bias[n];
        float a0 = b0, a1 = b0, a2 = b0, a3 = b0;
        const float* Bp = B + n;
        for (int k = 0; k < K; ++k) {
            float b = Bp[(size_t)k * N];
            a0 = fmaf(As[k], b, a0);
            a1 = fmaf(As[K + k], b, a1);
            a2 = fmaf(As[2 * K + k], b, a2);
            a3 = fmaf(As[3 * K + k], b, a3);
        }
        if (RELU) { a0 = fmaxf(a0, 0.f); a1 = fmaxf(a1, 0.f); a2 = fmaxf(a2, 0.f); a3 = fmaxf(a3, 0.f); }
        Cb[0 * ldc + n] = a0;
        Cb[1 * ldc + n] = a1;
        Cb[2 * ldc + n] = a2;
        Cb[3 * ldc + n] = a3;
    }
}

__global__ void final_linear2(const float* __restrict__ x, const float* __restrict__ W,
                              const float* __restrict__ b, float* __restrict__ out) {
    int i = blockIdx.x * blockDim.x + threadIdx.x;
    if (i >= B_GRAPH * 2) return;
    int row = i >> 1, o = i & 1;
    const float* xr = x + (size_t)row * 128;
    float acc = b[o];
    for (int k = 0; k < 128; ++k) acc = fmaf(xr[k], W[k * 2 + o], acc);
    out[i] = acc;
}

// ---------------------------------------------------------------------------
extern "C" void kernel_launch(void* const* d_in, const int* in_sizes, int n_in,
                              void* d_out, int out_size, void* d_ws, size_t ws_size,
                              hipStream_t stream) {
    (void)in_sizes; (void)n_in; (void)out_size; (void)ws_size;
    const float* x1   = (const float*)d_in[0];
    const int*   ei1  = (const int*)d_in[1];
    const float* x2   = (const float*)d_in[3];
    const int*   ei2  = (const int*)d_in[4];
    const float* cell = (const float*)d_in[6];
    const float* Wc1 = (const float*)d_in[7];  const float* bc1 = (const float*)d_in[8];
    const float* Wc2 = (const float*)d_in[9];  const float* bc2 = (const float*)d_in[10];
    const float* Wc3 = (const float*)d_in[11]; const float* bc3 = (const float*)d_in[12];
    const float* Wg1 = (const float*)d_in[13]; const float* bg1 = (const float*)d_in[14];
    const float* Wg2 = (const float*)d_in[15]; const float* bg2 = (const float*)d_in[16];
    const float* Wr1 = (const float*)d_in[17]; const float* br1 = (const float*)d_in[18];
    const float* Wr2 = (const float*)d_in[19]; const float* br2 = (const float*)d_in[20];
    const float* Wr3 = (const float*)d_in[21]; const float* br3 = (const float*)d_in[22];
    const float* Wf1 = (const float*)d_in[23]; const float* bf1 = (const float*)d_in[24];
    const float* Wf2 = (const float*)d_in[25]; const float* bf2 = (const float*)d_in[26];
    const float* Wo  = (const float*)d_in[27]; const float* bo  = (const float*)d_in[28];
    float* out = (float*)d_out;

    // ---- workspace: persistent (~11.5 MB) + union region ----
    float* ws = (float*)d_ws;
    float* xc   = ws;  ws += (size_t)B_GRAPH * 384;
    float* ssq  = ws;  ws += B_GRAPH;      // per-row sum of squares (cell)
    float* cv1  = ws;  ws += (size_t)B_GRAPH * 512;
    float* cv2  = ws;  ws += (size_t)B_GRAPH * 256;
    float* f1   = ws;  ws += (size_t)B_GRAPH * 512;
    float* f2   = ws;  ws += (size_t)B_GRAPH * 128;
    float* dinv = ws;  ws += NN2;
    float* pool = ws;  ws += (size_t)2048 * FXD4;
    float* gb   = ws;  ws += (size_t)2048 * FXD2;

    // union A: cell phase bf16 buffers (1536 x KP bf16 = 114.6 MB)
    us16* An  = (us16*)ws;
    us16* BwT = An + (size_t)B_GRAPH * KP;

    // union B: branch phase (used strictly after mfma_cell_gemm; ~81 MB)
    us16* Abuf = (us16*)ws;                        // gather out, NN2 x <=160 bf16
    us16* Hbuf = Abuf + (size_t)NN2 * 160;         // conv out,  NN2 x <=320 bf16
    us16* W1T  = Hbuf + (size_t)NN2 * 320;         // 80  x 96  (16B-aligned)
    us16* W2T  = W1T + 80 * 96;                    // 160 x 96
    us16* W3T  = W2T + 160 * 96;                   // 320 x 160
    float* enorm = (float*)(W3T + 320 * 160);
    int* cnt  = (int*)(enorm + EE2);
    int* cur  = cnt + NN2;
    int* base = cur + NN2;
    int* aux  = base + NN2 + 1;
    int* esrc = aux + 256;

    // ================= cell branch (bf16 MFMA) =================
    hipMemsetAsync(ssq, 0, (size_t)B_GRAPH * sizeof(float), stream);
    convert_cell_bf<<<dim3((KP / 8 + 255) / 256, B_GRAPH, 1), 256, 0, stream>>>(cell, An, ssq);
    convert_wT<<<dim3(KP / 32, 512 / 32, 1), 256, 0, stream>>>(Wr1, BwT, FXT, 512, KP);
    hipMemsetAsync(cv1, 0, (size_t)B_GRAPH * 512 * sizeof(float), stream);
    mfma_cell_gemm<<<dim3(8, 4, 16), 256, 0, stream>>>(An, BwT, ssq, cv1);
    // bias+relu on cv1 fused into the next gemv's A load (pre=br1, K=512 pow2)
    gemv_rows4<true><<<B_GRAPH / 4, 256, 0, stream>>>(cv1, Wr2, br2, br1, cv2, 512, 256, 256, 0);
    gemv_rows4<false><<<B_GRAPH / 4, 256, 0, stream>>>(cv2, Wr3, br3, nullptr, xc + 256, 256, OD, 384, 0);

    // ================= drug branches (batched, bf16 MFMA convs) =================
    hipMemsetAsync(cnt, 0, (size_t)2 * NN2 * sizeof(int), stream);   // cnt + cur
    deg_count_b<<<(EE2 + 255) / 256, 256, 0, stream>>>(ei1, ei2, cnt);
    scan1<<<NN2 / 512, 512, 0, stream>>>(cnt, base, aux, dinv);
    scan2<<<1, 256, 0, stream>>>(aux, NN2 / 512);
    scan3<<<NN2 / 512, 512, 0, stream>>>(base, aux);
    place_edges_b<<<(EE2 + 255) / 256, 256, 0, stream>>>(ei1, ei2, dinv, base, cur, esrc, enorm);

    // conv weights -> padded bf16 WT[n][k] (tiny; after cell phase frees union)
    convert_wT_small<<<(80 * 96 + 255) / 256, 256, 0, stream>>>(Wc1, W1T, FXD, FXD, 96, 80);
    convert_wT_small<<<(160 * 96 + 255) / 256, 256, 0, stream>>>(Wc2, W2T, FXD, FXD2, 96, 160);
    convert_wT_small<<<(320 * 160 + 255) / 256, 256, 0, stream>>>(Wc3, W3T, FXD2, FXD4, 160, 320);

    // conv1: gather(x) -> Abuf[96]; relu(Abuf@Wc1+bc1) -> Hbuf[80]
    gather_bf<float, 2><<<NN2 / 4, 256, 0, stream>>>(x1, x2, FXD, FXD, 96,
                                                     dinv, base, esrc, enorm, Abuf);
    mfma_conv<96><<<dim3(NN2 / 128, 1, 1), 256, 0, stream>>>(Abuf, W1T, bc1, Hbuf, FXD, 80);
    // conv2
    gather_bf<us16, 2><<<NN2 / 4, 256, 0, stream>>>(Hbuf, Hbuf + (size_t)N_NODES * 80, 80, FXD, 96,
                                                    dinv, base, esrc, enorm, Abuf);
    mfma_conv<96><<<dim3(NN2 / 128, 2, 1), 256, 0, stream>>>(Abuf, W2T, bc2, Hbuf, FXD2, 160);
    // conv3
    gather_bf<us16, 3><<<NN2 / 4, 256, 0, stream>>>(Hbuf, Hbuf + (size_t)N_NODES * 160, 160, FXD2, 160,
                                                    dinv, base, esrc, enorm, Abuf);
    mfma_conv<160><<<dim3(NN2 / 128, 4, 1), 256, 0, stream>>>(Abuf, W3T, bc3, Hbuf, FXD4, 320);

    // pool (2048 graphs) + fc
    seg_max_bf<<<dim3(2, 2048, 1), 256, 0, stream>>>(Hbuf, pool, FXD4, 320);
    gemv_rows4<true><<<2048 / 4, 256, 0, stream>>>(pool, Wg1, bg1, nullptr, gb, FXD4, FXD2, FXD2, 0);
    gemv_rows4<false><<<2048 / 4, 256, 0, stream>>>(gb, Wg2, bg2, nullptr, xc, FXD2, OD, 384, OD);

    // ================= final MLP =================
    gemv_rows4<true><<<B_GRAPH / 4, 256, 0, stream>>>(xc, Wf1, bf1, nullptr, f1, 384, 512, 512, 0);
    gemv_rows4<true><<<B_GRAPH / 4, 256, 0, stream>>>(f1, Wf2, bf2, nullptr, f2, 512, OD, OD, 0);
    final_linear2<<<(B_GRAPH * 2 + 255) / 256, 256, 0, stream>>>(f2, Wo, bo, out);
}

// Round 9
// 870.868 us; speedup vs baseline: 1.5628x; 1.2034x over previous
//
#include <hip/hip_runtime.h>

// Problem constants (fixed by setup_inputs).
constexpr int N_NODES = 40960;
constexpr int E_EDGES = 131072;
constexpr int B_GRAPH = 1024;
constexpr int FXD  = 78;
constexpr int FXD2 = 156;
constexpr int FXD4 = 312;
constexpr int OD   = 128;
constexpr int FXT  = 37261;
constexpr int KP   = 37312;            // FXT padded to mult of 64 (BK=64 cell GEMM)
constexpr int NPG  = N_NODES / B_GRAPH;
constexpr int NN2  = 2 * N_NODES;      // batched (both drug branches)
constexpr int EE2  = 2 * E_EDGES;

typedef unsigned short us16;
typedef __attribute__((ext_vector_type(8))) short short8;  // 8 bf16
typedef __attribute__((ext_vector_type(4))) float f32x4;

__device__ inline us16 f2bf(float f) {             // fp32 -> bf16 RNE
    unsigned u = __float_as_uint(f);
    return (us16)((u + 0x7FFF + ((u >> 16) & 1)) >> 16);
}
__device__ inline float ldf(const float* p) { return *p; }
__device__ inline float ldf(const us16* p) { return __uint_as_float(((unsigned)*p) << 16); }

// ---------------------------------------------------------------------------
// Cell-layer bf16 MFMA GEMM: cv1[1024x512] += (An[1024xKP] @ BwT^T) * invn[row]
// invn[row] = 1/max(sqrt(ssq[row]),1e-12) applied in epilogue (split-K safe).
// BK=64, split-K z=16, double-buffered LDS filled via async global_load_lds
// (width=16, no VGPR staging -> no spill risk). One barrier per K-step.
// Swizzle is both-sides (rule #21): LDS dest linear, SOURCE chunk permuted
// (l&7)^(l>>3); reads apply chunk ^ (lane&7). ~2-way LDS conflicts (free).
// PROVEN (R8): dropped below the 87 us tier (was 121 us).
// ---------------------------------------------------------------------------
#define CG_STAGE(buf, s)                                                       \
    {                                                                          \
        _Pragma("unroll")                                                      \
        for (int i = 0; i < 4; ++i) {                                          \
            __builtin_amdgcn_global_load_lds(                                  \
                (const __attribute__((address_space(1))) unsigned*)            \
                    (Ag + (size_t)i * 8 * KP + (size_t)(s) * 64),              \
                (__attribute__((address_space(3))) unsigned*)                  \
                    &As[buf][wave * 32 + i * 8][0], 16, 0, 0);                 \
            __builtin_amdgcn_global_load_lds(                                  \
                (const __attribute__((address_space(1))) unsigned*)            \
                    (Bg + (size_t)i * 8 * KP + (size_t)(s) * 64),              \
                (__attribute__((address_space(3))) unsigned*)                  \
                    &Bs[buf][wave * 32 + i * 8][0], 16, 0, 0);                 \
        }                                                                      \
    }

__global__ __launch_bounds__(256, 2)
void mfma_cell_gemm(const us16* __restrict__ An, const us16* __restrict__ BwT,
                    const float* __restrict__ ssq, float* __restrict__ C)
{
    __shared__ us16 As[2][128][64];     // 32 KB
    __shared__ us16 Bs[2][128][64];     // 32 KB
    const int tid = threadIdx.x;
    const int m0 = blockIdx.x * 128;          // gx = 8
    const int n0 = blockIdx.y * 128;          // gy = 4
    const int S  = KP / 64;                   // 583
    const int per = (S + gridDim.z - 1) / gridDim.z;
    const int s0 = blockIdx.z * per;
    const int s1 = min(S, s0 + per);

    const int wave = tid >> 6, lane = tid & 63;
    // staging: wave w instr i fills LDS rows [w*32+i*8, +8), lane l -> row +l>>3,
    // chunk slot l&7; source chunk = (l&7)^(l>>3) so slot c holds chunk c^(row&7)
    const int srow = lane >> 3;
    const int swz  = (lane & 7) ^ srow;
    const us16* Ag = An  + (size_t)(m0 + wave * 32 + srow) * KP + swz * 8;
    const us16* Bg = BwT + (size_t)(n0 + wave * 32 + srow) * KP + swz * 8;

    const int wm = (wave >> 1) * 64, wn = (wave & 1) * 64;
    const int fr = lane & 15, fq8 = (lane >> 4);   // fragment chunk within substep
    const int sx = lane & 7;                       // read-side xor = row&7

    f32x4 acc[4][4] = {};

    CG_STAGE(0, s0)
    __syncthreads();
    int cb = 0;
    for (int s = s0; s < s1; ++s) {
        if (s + 1 < s1) CG_STAGE(cb ^ 1, s + 1)    // async; lands by next barrier
#pragma unroll
        for (int ks = 0; ks < 2; ++ks) {           // two K=32 substeps
            const int c = ks * 4 + fq8;            // logical chunk 0..7
            short8 af[4], bf[4];
#pragma unroll
            for (int t = 0; t < 4; ++t) {
                af[t] = *(const short8*)&As[cb][wm + t * 16 + fr][(c ^ sx) * 8];
                bf[t] = *(const short8*)&Bs[cb][wn + t * 16 + fr][(c ^ sx) * 8];
            }
#pragma unroll
            for (int mt = 0; mt < 4; ++mt)
#pragma unroll
                for (int nt = 0; nt < 4; ++nt)
                    acc[mt][nt] = __builtin_amdgcn_mfma_f32_16x16x32_bf16(
                        af[mt], bf[nt], acc[mt][nt], 0, 0, 0);
        }
        __syncthreads();                           // drains vmcnt -> next buf ready
        cb ^= 1;
    }

    // per-row normalization scale (const-indexed -> regs)
    float rs[4][4];
#pragma unroll
    for (int mt = 0; mt < 4; ++mt)
#pragma unroll
        for (int reg = 0; reg < 4; ++reg) {
            int row = m0 + wm + mt * 16 + (lane >> 4) * 4 + reg;
            rs[mt][reg] = 1.0f / fmaxf(sqrtf(ssq[row]), 1e-12f);
        }
#pragma unroll
    for (int mt = 0; mt < 4; ++mt)
#pragma unroll
        for (int nt = 0; nt < 4; ++nt)
#pragma unroll
            for (int reg = 0; reg < 4; ++reg) {
                int row = m0 + wm + mt * 16 + (lane >> 4) * 4 + reg;
                int col = n0 + wn + nt * 16 + fr;
                atomicAdd(&C[(size_t)row * 512 + col], acc[mt][nt][reg] * rs[mt][reg]);
            }
}

// Single-pass stream: An[row][k] = bf16(cell[row][k]) (UNnormalized), zero-pad
// to KP; per-block partial sum of fp32 squares atomicAdd'ed into ssq[row].
__global__ __launch_bounds__(256)
void convert_cell_bf(const float* __restrict__ cell, us16* __restrict__ An,
                     float* __restrict__ ssq)
{
    const int row = blockIdx.y;
    const int k8 = (blockIdx.x * 256 + threadIdx.x) * 8;
    const float* src = cell + (size_t)row * FXT;
    float ps = 0.f;
    if (k8 < KP) {
        us16 v[8];
#pragma unroll
        for (int j = 0; j < 8; ++j) {
            int k = k8 + j;
            float x = (k < FXT) ? src[k] : 0.0f;
            ps = fmaf(x, x, ps);
            v[j] = f2bf(x);
        }
        *(uint4*)&An[(size_t)row * KP + k8] = *(uint4*)v;
    }
    for (int off = 32; off > 0; off >>= 1) ps += __shfl_down(ps, off, 64);
    __shared__ float sred[4];
    const int lane = threadIdx.x & 63, wv = threadIdx.x >> 6;
    if (lane == 0) sred[wv] = ps;
    __syncthreads();
    if (threadIdx.x == 0)
        atomicAdd(&ssq[row], sred[0] + sred[1] + sred[2] + sred[3]);
}

// WT[n][k] = bf16(W[k][n]), k zero-padded to KPc. 32x32 tiled transpose.
__global__ __launch_bounds__(256)
void convert_wT(const float* __restrict__ W, us16* __restrict__ WT,
                int K, int Nn, int KPc)
{
    __shared__ float tile[32][33];
    const int k0 = blockIdx.x * 32;
    const int n0 = blockIdx.y * 32;
    const int c  = threadIdx.x & 31;
    const int r0 = threadIdx.x >> 5;
#pragma unroll
    for (int p = 0; p < 4; ++p) {
        int k = k0 + r0 + p * 8;
        tile[r0 + p * 8][c] = (k < K && n0 + c < Nn) ? W[(size_t)k * Nn + n0 + c] : 0.0f;
    }
    __syncthreads();
#pragma unroll
    for (int p = 0; p < 4; ++p) {
        int n = n0 + r0 + p * 8;
        if (n < Nn) WT[(size_t)n * KPc + k0 + c] = f2bf(tile[c][r0 + p * 8]);
    }
}

// Small padded weight transpose: WT[n][k] bf16, n in [0,NPr), k in [0,KPc),
// zero-filled outside the real K x Nn extent. Tiny matrices only.
__global__ void convert_wT_small(const float* __restrict__ W, us16* __restrict__ WT,
                                 int K, int Nn, int KPc, int NPr)
{
    int idx = blockIdx.x * 256 + threadIdx.x;
    if (idx >= NPr * KPc) return;
    int n = idx / KPc, k = idx - n * KPc;
    WT[idx] = (n < Nn && k < K) ? f2bf(W[(size_t)k * Nn + n]) : (us16)0;
}

// ---------------------------------------------------------------------------
// Drug-conv bf16 MFMA GEMM: C = relu(A @ WT^T + bias), bf16 out.
// A: [NN2][KA] bf16 (zero-padded K). WT: [NP][KA] bf16 (zero-padded rows).
// Block: 256 thr / 4 waves; BM=128 (wave=32 rows); NTILE=80 (5 n-frags).
// Whole B tile in LDS; A double-buffered per 32-k step.
// ---------------------------------------------------------------------------
template<int KA>
__global__ __launch_bounds__(256, 2)
void mfma_conv(const us16* __restrict__ A, const us16* __restrict__ BT,
               const float* __restrict__ bias, us16* __restrict__ C,
               int Nn, int ldc)
{
    constexpr int KS = KA / 32;
    __shared__ us16 As[2][128][40];
    __shared__ us16 Bs[80][KA + 8];
    const int tid = threadIdx.x;
    const int m0 = blockIdx.x * 128;
    const int n0 = blockIdx.y * 80;

    // B tile (80 x KA), read-once (hot in L2 across blocks)
    for (int idx = tid; idx < 80 * (KA / 8); idx += 256) {
        int nr = idx / (KA / 8), c8 = (idx - nr * (KA / 8)) * 8;
        *(uint4*)&Bs[nr][c8] = *(const uint4*)&BT[(size_t)(n0 + nr) * KA + c8];
    }

    const int r = tid >> 1, h = (tid & 1) * 16;
    const us16* Ap = A + (size_t)(m0 + r) * KA + h;
    *(uint4*)&As[0][r][h]     = *(const uint4*)Ap;
    *(uint4*)&As[0][r][h + 8] = *(const uint4*)(Ap + 8);
    __syncthreads();

    const int wave = tid >> 6, lane = tid & 63;
    const int wm = wave * 32;
    const int fr = lane & 15, fq = (lane >> 4) * 8;

    f32x4 acc[2][5] = {};
#pragma unroll
    for (int s = 0; s < KS; ++s) {
        const int cb = s & 1;
        if (s + 1 < KS) {                    // prefetch next chunk into other buffer
            uint4 t0 = *(const uint4*)(Ap + 32);
            uint4 t1 = *(const uint4*)(Ap + 40);
            Ap += 32;
            *(uint4*)&As[cb ^ 1][r][h]     = t0;
            *(uint4*)&As[cb ^ 1][r][h + 8] = t1;
        }
        short8 af[2], bf[5];
#pragma unroll
        for (int mt = 0; mt < 2; ++mt)
            af[mt] = *(const short8*)&As[cb][wm + mt * 16 + fr][fq];
#pragma unroll
        for (int nf = 0; nf < 5; ++nf)
            bf[nf] = *(const short8*)&Bs[nf * 16 + fr][s * 32 + fq];
#pragma unroll
        for (int mt = 0; mt < 2; ++mt)
#pragma unroll
            for (int nf = 0; nf < 5; ++nf)
                acc[mt][nf] = __builtin_amdgcn_mfma_f32_16x16x32_bf16(
                    af[mt], bf[nf], acc[mt][nf], 0, 0, 0);
        __syncthreads();
    }

#pragma unroll
    for (int mt = 0; mt < 2; ++mt)
#pragma unroll
        for (int nf = 0; nf < 5; ++nf) {
            const int col = n0 + nf * 16 + fr;
            if (col < Nn) {
                const float bv = bias[col];
#pragma unroll
                for (int reg = 0; reg < 4; ++reg) {
                    int row = m0 + wm + mt * 16 + (lane >> 4) * 4 + reg;
                    C[(size_t)row * ldc + col] = f2bf(fmaxf(acc[mt][nf][reg] + bv, 0.0f));
                }
            }
        }
}

// ---------------------------------------------------------------------------
// Batched (both graphs) edge sort + gather aggregation.
// ---------------------------------------------------------------------------
__global__ void deg_count_b(const int* __restrict__ ei1, const int* __restrict__ ei2,
                            int* cnt) {
    int i = blockIdx.x * blockDim.x + threadIdx.x;
    if (i >= EE2) return;
    int d = (i < E_EDGES) ? ei1[E_EDGES + i] : ei2[E_EDGES + (i - E_EDGES)] + N_NODES;
    atomicAdd(&cnt[d], 1);
}

__global__ __launch_bounds__(512)
void scan1(const int* __restrict__ cnt, int* base, int* aux, float* dinv) {
    __shared__ int s[512];
    const int tid = threadIdx.x;
    const int i = blockIdx.x * 512 + tid;
    int v = cnt[i];
    dinv[i] = rsqrtf((float)(v + 1));
    s[tid] = v;
    __syncthreads();
    for (int off = 1; off < 512; off <<= 1) {
        int t = (tid >= off) ? s[tid - off] : 0;
        __syncthreads();
        s[tid] += t;
        __syncthreads();
    }
    base[i] = s[tid] - v;
    if (tid == 511) aux[blockIdx.x] = s[511];
}

__global__ void scan2(int* aux, int nblk) {
    __shared__ int s[256];
    const int tid = threadIdx.x;
    int v = (tid < nblk) ? aux[tid] : 0;
    s[tid] = v;
    __syncthreads();
    for (int off = 1; off < 256; off <<= 1) {
        int t = (tid >= off) ? s[tid - off] : 0;
        __syncthreads();
        s[tid] += t;
        __syncthreads();
    }
    if (tid < nblk) aux[tid] = s[tid] - v;
}

__global__ __launch_bounds__(512)
void scan3(int* base, const int* __restrict__ aux) {
    int i = blockIdx.x * 512 + threadIdx.x;
    base[i] += aux[blockIdx.x];
    if (i == 0) base[NN2] = EE2;
}

__global__ void place_edges_b(const int* __restrict__ ei1, const int* __restrict__ ei2,
                              const float* __restrict__ dinv, const int* __restrict__ base,
                              int* cur, int* __restrict__ esrc, float* __restrict__ enorm) {
    int e = blockIdx.x * blockDim.x + threadIdx.x;
    if (e >= EE2) return;
    int s, d;
    if (e < E_EDGES) { s = ei1[e];            d = ei1[E_EDGES + e]; }
    else             { s = ei2[e - E_EDGES] + N_NODES;
                       d = ei2[E_EDGES + (e - E_EDGES)] + N_NODES; }
    int p = base[d] + atomicAdd(&cur[d], 1);
    esrc[p]  = s;
    enorm[p] = dinv[s] * dinv[d];
}

// out[row][0:kaout] = bf16( sum_edges h[src]*norm + h[row]*dinv^2 ), zero pad.
template<typename Tin, int CH>
__global__ __launch_bounds__(256)
void gather_bf(const Tin* __restrict__ hA, const Tin* __restrict__ hB, int st, int fi, int kaout,
               const float* __restrict__ dinv, const int* __restrict__ base,
               const int* __restrict__ esrc, const float* __restrict__ enorm,
               us16* __restrict__ out)
{
    const int row  = blockIdx.x * 4 + (threadIdx.x >> 6);
    const int lane = threadIdx.x & 63;
    const float d  = dinv[row];
    const float d2 = d * d;
    const Tin* hr = (row < N_NODES) ? hA + (size_t)row * st
                                    : hB + (size_t)(row - N_NODES) * st;
    float acc[CH];
#pragma unroll
    for (int c = 0; c < CH; ++c) {
        int f = lane + 64 * c;
        acc[c] = (f < fi) ? ldf(hr + f) * d2 : 0.0f;
    }
    const int b0 = base[row], b1 = base[row + 1];
    for (int j = b0; j < b1; ++j) {
        const int s = esrc[j];
        const float w = enorm[j];
        const Tin* hs = (s < N_NODES) ? hA + (size_t)s * st
                                      : hB + (size_t)(s - N_NODES) * st;
#pragma unroll
        for (int c = 0; c < CH; ++c) {
            int f = lane + 64 * c;
            if (f < fi) acc[c] = fmaf(ldf(hs + f), w, acc[c]);
        }
    }
    us16* orow = out + (size_t)row * kaout;
#pragma unroll
    for (int c = 0; c < CH; ++c) {
        int f = lane + 64 * c;
        if (f < kaout) orow[f] = f2bf(acc[c]);   // acc==0 for f>=fi -> zero pad
    }
}

// ---------------------------------------------------------------------------
__global__ void seg_max_bf(const us16* __restrict__ x, float* __restrict__ out,
                           int fo, int ld) {
    int f = blockIdx.x * blockDim.x + threadIdx.x;
    int g = blockIdx.y;
    if (f >= fo) return;
    const us16* xp = x + (size_t)g * NPG * ld + f;
    float v = -1e30f;
#pragma unroll 4
    for (int j = 0; j < NPG; ++j) v = fmaxf(v, ldf(xp + (size_t)j * ld));
    out[(size_t)g * fo + f] = v;
}

// ---------------------------------------------------------------------------
// Wide skinny-GEMM: C[M x N] = act(A @ B + bias), fp32.
// grid (M/4, ceil(N/128)); 256 thr = 32 col-slots (4 cols, float4 B loads)
// x 8 K-groups. 16 indep acc chains/thread; LDS reduce over K-groups.
// Replaces gemv_rows4 (88 us @ xc->f1: 1 blk/CU, serial K chain, L2-latency
// bound). pre != null (K pow2): relu(A+pre) fused on A load.
// half_off != 0: rows >= 1024 map to row-1024, column offset half_off.
// ---------------------------------------------------------------------------
template<bool RELU>
__global__ __launch_bounds__(256)
void gemv_wide(const float* __restrict__ A, const float* __restrict__ B,
               const float* __restrict__ bias, const float* __restrict__ pre,
               float* __restrict__ C, int K, int N, int ldc, int half_off)
{
    __shared__ float As[4 * 512];
    __shared__ float red[256][16];
    const int tid = threadIdx.x;
    const int r0 = blockIdx.x * 4;
    const int n0 = blockIdx.y * 128;
    if (pre) {
        for (int i = tid; i < 4 * K; i += 256)
            As[i] = fmaxf(A[(size_t)r0 * K + i] + pre[i & (K - 1)], 0.0f);
    } else {
        for (int i = tid; i < 4 * K; i += 256) As[i] = A[(size_t)r0 * K + i];
    }
    __syncthreads();

    const int s = tid & 31;              // column slot (4 cols)
    const int g = tid >> 5;              // K-group 0..7
    const int col = n0 + s * 4;
    const int Kc = (K + 7) >> 3;
    const int k0 = g * Kc;
    const int k1 = min(K, k0 + Kc);

    float4 a0 = {0,0,0,0}, a1 = {0,0,0,0}, a2 = {0,0,0,0}, a3 = {0,0,0,0};
    if (col < N) {
#pragma unroll 2
        for (int k = k0; k < k1; ++k) {
            float4 b = *(const float4*)&B[(size_t)k * N + col];
            float v0 = As[k], v1 = As[K + k], v2 = As[2 * K + k], v3 = As[3 * K + k];
            a0.x = fmaf(v0, b.x, a0.x); a0.y = fmaf(v0, b.y, a0.y);
            a0.z = fmaf(v0, b.z, a0.z); a0.w = fmaf(v0, b.w, a0.w);
            a1.x = fmaf(v1, b.x, a1.x); a1.y = fmaf(v1, b.y, a1.y);
            a1.z = fmaf(v1, b.z, a1.z); a1.w = fmaf(v1, b.w, a1.w);
            a2.x = fmaf(v2, b.x, a2.x); a2.y = fmaf(v2, b.y, a2.y);
            a2.z = fmaf(v2, b.z, a2.z); a2.w = fmaf(v2, b.w, a2.w);
            a3.x = fmaf(v3, b.x, a3.x); a3.y = fmaf(v3, b.y, a3.y);
            a3.z = fmaf(v3, b.z, a3.z); a3.w = fmaf(v3, b.w, a3.w);
        }
    }
    *(float4*)&red[tid][0]  = a0;
    *(float4*)&red[tid][4]  = a1;
    *(float4*)&red[tid][8]  = a2;
    *(float4*)&red[tid][12] = a3;
    __syncthreads();

    if (g == 0 && col < N) {
        float4 s0 = {0,0,0,0}, s1 = {0,0,0,0}, s2 = {0,0,0,0}, s3 = {0,0,0,0};
#pragma unroll
        for (int gg = 0; gg < 8; ++gg) {
            const float* rp = &red[gg * 32 + s][0];
            float4 t0 = *(const float4*)&rp[0];
            float4 t1 = *(const float4*)&rp[4];
            float4 t2 = *(const float4*)&rp[8];
            float4 t3 = *(const float4*)&rp[12];
            s0.x += t0.x; s0.y += t0.y; s0.z += t0.z; s0.w += t0.w;
            s1.x += t1.x; s1.y += t1.y; s1.z += t1.z; s1.w += t1.w;
            s2.x += t2.x; s2.y += t2.y; s2.z += t2.z; s2.w += t2.w;
            s3.x += t3.x; s3.y += t3.y; s3.z += t3.z; s3.w += t3.w;
        }
        float4 bv = *(const float4*)&bias[col];
        s0.x += bv.x; s0.y += bv.y; s0.z += bv.z; s0.w += bv.w;
        s1.x += bv.x; s1.y += bv.y; s1.z += bv.z; s1.w += bv.w;
        s2.x += bv.x; s2.y += bv.y; s2.z += bv.z; s2.w += bv.w;
        s3.x += bv.x; s3.y += bv.y; s3.z += bv.z; s3.w += bv.w;
        if (RELU) {
            s0.x = fmaxf(s0.x, 0.f); s0.y = fmaxf(s0.y, 0.f); s0.z = fmaxf(s0.z, 0.f); s0.w = fmaxf(s0.w, 0.f);
            s1.x = fmaxf(s1.x, 0.f); s1.y = fmaxf(s1.y, 0.f); s1.z = fmaxf(s1.z, 0.f); s1.w = fmaxf(s1.w, 0.f);
            s2.x = fmaxf(s2.x, 0.f); s2.y = fmaxf(s2.y, 0.f); s2.z = fmaxf(s2.z, 0.f); s2.w = fmaxf(s2.w, 0.f);
            s3.x = fmaxf(s3.x, 0.f); s3.y = fmaxf(s3.y, 0.f); s3.z = fmaxf(s3.z, 0.f); s3.w = fmaxf(s3.w, 0.f);
        }
        float* Cb;
        if (half_off != 0)
            Cb = C + (size_t)(r0 & 1023) * ldc + ((r0 >= 1024) ? half_off : 0);
        else
            Cb = C + (size_t)r0 * ldc;
        *(float4*)&Cb[0 * ldc + col] = s0;
        *(float4*)&Cb[1 * ldc + col] = s1;
        *(float4*)&Cb[2 * ldc + col] = s2;
        *(float4*)&Cb[3 * ldc + col] = s3;
    }
}

__global__ void final_linear2(const float* __restrict__ x, const float* __restrict__ W,
                              const float* __restrict__ b, float* __restrict__ out) {
    int i = blockIdx.x * blockDim.x + threadIdx.x;
    if (i >= B_GRAPH * 2) return;
    int row = i >> 1, o = i & 1;
    const float* xr = x + (size_t)row * 128;
    float acc = b[o];
    for (int k = 0; k < 128; ++k) acc = fmaf(xr[k], W[k * 2 + o], acc);
    out[i] = acc;
}

// ---------------------------------------------------------------------------
extern "C" void kernel_launch(void* const* d_in, const int* in_sizes, int n_in,
                              void* d_out, int out_size, void* d_ws, size_t ws_size,
                              hipStream_t stream) {
    (void)in_sizes; (void)n_in; (void)out_size; (void)ws_size;
    const float* x1   = (const float*)d_in[0];
    const int*   ei1  = (const int*)d_in[1];
    const float* x2   = (const float*)d_in[3];
    const int*   ei2  = (const int*)d_in[4];
    const float* cell = (const float*)d_in[6];
    const float* Wc1 = (const float*)d_in[7];  const float* bc1 = (const float*)d_in[8];
    const float* Wc2 = (const float*)d_in[9];  const float* bc2 = (const float*)d_in[10];
    const float* Wc3 = (const float*)d_in[11]; const float* bc3 = (const float*)d_in[12];
    const float* Wg1 = (const float*)d_in[13]; const float* bg1 = (const float*)d_in[14];
    const float* Wg2 = (const float*)d_in[15]; const float* bg2 = (const float*)d_in[16];
    const float* Wr1 = (const float*)d_in[17]; const float* br1 = (const float*)d_in[18];
    const float* Wr2 = (const float*)d_in[19]; const float* br2 = (const float*)d_in[20];
    const float* Wr3 = (const float*)d_in[21]; const float* br3 = (const float*)d_in[22];
    const float* Wf1 = (const float*)d_in[23]; const float* bf1 = (const float*)d_in[24];
    const float* Wf2 = (const float*)d_in[25]; const float* bf2 = (const float*)d_in[26];
    const float* Wo  = (const float*)d_in[27]; const float* bo  = (const float*)d_in[28];
    float* out = (float*)d_out;

    // ---- workspace: persistent (~11.5 MB) + union region ----
    float* ws = (float*)d_ws;
    float* xc   = ws;  ws += (size_t)B_GRAPH * 384;
    float* ssq  = ws;  ws += B_GRAPH;      // per-row sum of squares (cell)
    float* cv1  = ws;  ws += (size_t)B_GRAPH * 512;
    float* cv2  = ws;  ws += (size_t)B_GRAPH * 256;
    float* f1   = ws;  ws += (size_t)B_GRAPH * 512;
    float* f2   = ws;  ws += (size_t)B_GRAPH * 128;
    float* dinv = ws;  ws += NN2;
    float* pool = ws;  ws += (size_t)2048 * FXD4;
    float* gb   = ws;  ws += (size_t)2048 * FXD2;

    // union A: cell phase bf16 buffers (1536 x KP bf16 = 114.6 MB)
    us16* An  = (us16*)ws;
    us16* BwT = An + (size_t)B_GRAPH * KP;

    // union B: branch phase (used strictly after mfma_cell_gemm; ~81 MB)
    us16* Abuf = (us16*)ws;                        // gather out, NN2 x <=160 bf16
    us16* Hbuf = Abuf + (size_t)NN2 * 160;         // conv out,  NN2 x <=320 bf16
    us16* W1T  = Hbuf + (size_t)NN2 * 320;         // 80  x 96  (16B-aligned)
    us16* W2T  = W1T + 80 * 96;                    // 160 x 96
    us16* W3T  = W2T + 160 * 96;                   // 320 x 160
    float* enorm = (float*)(W3T + 320 * 160);
    int* cnt  = (int*)(enorm + EE2);
    int* cur  = cnt + NN2;
    int* base = cur + NN2;
    int* aux  = base + NN2 + 1;
    int* esrc = aux + 256;

    // ================= cell branch (bf16 MFMA) =================
    hipMemsetAsync(ssq, 0, (size_t)B_GRAPH * sizeof(float), stream);
    convert_cell_bf<<<dim3((KP / 8 + 255) / 256, B_GRAPH, 1), 256, 0, stream>>>(cell, An, ssq);
    convert_wT<<<dim3(KP / 32, 512 / 32, 1), 256, 0, stream>>>(Wr1, BwT, FXT, 512, KP);
    hipMemsetAsync(cv1, 0, (size_t)B_GRAPH * 512 * sizeof(float), stream);
    mfma_cell_gemm<<<dim3(8, 4, 16), 256, 0, stream>>>(An, BwT, ssq, cv1);
    // bias+relu on cv1 fused into the next gemv's A load (pre=br1, K=512 pow2)
    gemv_wide<true><<<dim3(B_GRAPH / 4, 2), 256, 0, stream>>>(cv1, Wr2, br2, br1, cv2, 512, 256, 256, 0);
    gemv_wide<false><<<dim3(B_GRAPH / 4, 1), 256, 0, stream>>>(cv2, Wr3, br3, nullptr, xc + 256, 256, OD, 384, 0);

    // ================= drug branches (batched, bf16 MFMA convs) =================
    hipMemsetAsync(cnt, 0, (size_t)2 * NN2 * sizeof(int), stream);   // cnt + cur
    deg_count_b<<<(EE2 + 255) / 256, 256, 0, stream>>>(ei1, ei2, cnt);
    scan1<<<NN2 / 512, 512, 0, stream>>>(cnt, base, aux, dinv);
    scan2<<<1, 256, 0, stream>>>(aux, NN2 / 512);
    scan3<<<NN2 / 512, 512, 0, stream>>>(base, aux);
    place_edges_b<<<(EE2 + 255) / 256, 256, 0, stream>>>(ei1, ei2, dinv, base, cur, esrc, enorm);

    // conv weights -> padded bf16 WT[n][k] (tiny; after cell phase frees union)
    convert_wT_small<<<(80 * 96 + 255) / 256, 256, 0, stream>>>(Wc1, W1T, FXD, FXD, 96, 80);
    convert_wT_small<<<(160 * 96 + 255) / 256, 256, 0, stream>>>(Wc2, W2T, FXD, FXD2, 96, 160);
    convert_wT_small<<<(320 * 160 + 255) / 256, 256, 0, stream>>>(Wc3, W3T, FXD2, FXD4, 160, 320);

    // conv1: gather(x) -> Abuf[96]; relu(Abuf@Wc1+bc1) -> Hbuf[80]
    gather_bf<float, 2><<<NN2 / 4, 256, 0, stream>>>(x1, x2, FXD, FXD, 96,
                                                     dinv, base, esrc, enorm, Abuf);
    mfma_conv<96><<<dim3(NN2 / 128, 1, 1), 256, 0, stream>>>(Abuf, W1T, bc1, Hbuf, FXD, 80);
    // conv2
    gather_bf<us16, 2><<<NN2 / 4, 256, 0, stream>>>(Hbuf, Hbuf + (size_t)N_NODES * 80, 80, FXD, 96,
                                                    dinv, base, esrc, enorm, Abuf);
    mfma_conv<96><<<dim3(NN2 / 128, 2, 1), 256, 0, stream>>>(Abuf, W2T, bc2, Hbuf, FXD2, 160);
    // conv3
    gather_bf<us16, 3><<<NN2 / 4, 256, 0, stream>>>(Hbuf, Hbuf + (size_t)N_NODES * 160, 160, FXD2, 160,
                                                    dinv, base, esrc, enorm, Abuf);
    mfma_conv<160><<<dim3(NN2 / 128, 4, 1), 256, 0, stream>>>(Abuf, W3T, bc3, Hbuf, FXD4, 320);

    // pool (2048 graphs) + fc
    seg_max_bf<<<dim3(2, 2048, 1), 256, 0, stream>>>(Hbuf, pool, FXD4, 320);
    gemv_wide<true><<<dim3(2048 / 4, 2), 256, 0, stream>>>(pool, Wg1, bg1, nullptr, gb, FXD4, FXD2, FXD2, 0);
    gemv_wide<false><<<dim3(2048 / 4, 1), 256, 0, stream>>>(gb, Wg2, bg2, nullptr, xc, FXD2, OD, 384, OD);

    // ================= final MLP =================
    gemv_wide<true><<<dim3(B_GRAPH / 4, 4), 256, 0, stream>>>(xc, Wf1, bf1, nullptr, f1, 384, 512, 512, 0);
    gemv_wide<true><<<dim3(B_GRAPH / 4, 1), 256, 0, stream>>>(f1, Wf2, bf2, nullptr, f2, 512, OD, OD, 0);
    final_linear2<<<(B_GRAPH * 2 + 255) / 256, 256, 0, stream>>>(f2, Wo, bo, out);
}